// Round 5
// baseline (967.364 us; speedup 1.0000x reference)
//
#include <hip/hip_runtime.h>
#include <math.h>

#define B_   4
#define C_   256
#define G_   32
#define CPG  8                 // channels per group
#define N_   4096              // H*W
#define NPG  (CPG * N_)        // 32768 elements per group
#define EPS  1e-5f
#define SCALE 0.0625f          // C^-0.5 = 1/16
#define NCH2 8                 // chunks of 128 keys per split quarter (1024 keys)

typedef __attribute__((ext_vector_type(8)))  __bf16 bf16x8;
typedef __attribute__((ext_vector_type(4)))  __bf16 bf16x4;
typedef __attribute__((ext_vector_type(16))) float  f32x16;

// ---------------------------------------------------------------------------
// Kernel 1a: GroupNorm partial sums (unchanged).
// ---------------------------------------------------------------------------
__global__ __launch_bounds__(256) void gn_stats_kernel(const float* __restrict__ x,
                                                       float* __restrict__ part) {
    int bid = blockIdx.x;
    int bg = bid >> 2, seg = bid & 3;
    const float4* xp4 = (const float4*)(x + (size_t)bg * NPG) + seg * 2048;
    int tid = threadIdx.x;

    float s = 0.f, ss = 0.f;
    for (int i = tid; i < 2048; i += 256) {
        float4 t = xp4[i];
        s  += t.x + t.y + t.z + t.w;
        ss += t.x * t.x + t.y * t.y + t.z * t.z + t.w * t.w;
    }
    #pragma unroll
    for (int off = 32; off; off >>= 1) {
        s  += __shfl_xor(s, off, 64);
        ss += __shfl_xor(ss, off, 64);
    }
    __shared__ float rs[2][4];
    int wave = tid >> 6, lane = tid & 63;
    if (lane == 0) { rs[0][wave] = s; rs[1][wave] = ss; }
    __syncthreads();
    if (tid == 0) {
        part[bid * 2]     = rs[0][0] + rs[0][1] + rs[0][2] + rs[0][3];
        part[bid * 2 + 1] = rs[1][0] + rs[1][1] + rs[1][2] + rs[1][3];
    }
}

// ---------------------------------------------------------------------------
// Kernel 1b: GroupNorm apply -> bf16 frag-interleaved (unchanged).
// ---------------------------------------------------------------------------
__global__ __launch_bounds__(256) void gn_apply_kernel(const float* __restrict__ x,
                                                       const float* __restrict__ w,
                                                       const float* __restrict__ bia,
                                                       const float* __restrict__ part,
                                                       __bf16* __restrict__ xnb) {
    int bid = blockIdx.x;
    int bg = bid >> 4, seg = bid & 15;
    int b = bg >> 5, g = bg & 31;
    float s  = part[(bg * 4 + 0) * 2] + part[(bg * 4 + 1) * 2]
             + part[(bg * 4 + 2) * 2] + part[(bg * 4 + 3) * 2];
    float ss = part[(bg * 4 + 0) * 2 + 1] + part[(bg * 4 + 1) * 2 + 1]
             + part[(bg * 4 + 2) * 2 + 1] + part[(bg * 4 + 3) * 2 + 1];
    float mean = s / (float)NPG;
    float var  = ss / (float)NPG - mean * mean;
    float rstd = rsqrtf(var + EPS);

    const float* xp = x + (size_t)bg * NPG;
    int n = seg * 256 + threadIdx.x;

    bf16x8 pk;
    #pragma unroll
    for (int cc = 0; cc < 8; cc++) {
        float sc = rstd * w[g * CPG + cc];
        float sh = bia[g * CPG + cc] - mean * sc;
        pk[cc] = (__bf16)(xp[(size_t)cc * N_ + n] * sc + sh);
    }
    size_t idx = ((((size_t)(b * 128 + (n >> 5)) * 16 + (g >> 1)) * 2 + (g & 1))
                  * 32 + (n & 31)) * 8;
    *(bf16x8*)(xnb + idx) = pk;
}

// ---------------------------------------------------------------------------
// Kernel 2: QKV projection, bf16 MFMA (unchanged).
// ---------------------------------------------------------------------------
__global__ __launch_bounds__(256) void qkv_kernel(const __bf16* __restrict__ xnb,
                                                  const float* __restrict__ W,
                                                  const float* __restrict__ bias,
                                                  __bf16* __restrict__ q,
                                                  __bf16* __restrict__ k,
                                                  __bf16* __restrict__ v) {
    int b = blockIdx.z, ot = blockIdx.y, nc = blockIdx.x;
    int tid = threadIdx.x, wv = tid >> 6, lane = tid & 63;
    int n31 = lane & 31, q2 = lane >> 5;
    int B0 = ot * 128 + wv * 32;

    bf16x8 wf[16];
    const float* wp = W + (size_t)(B0 + n31) * C_;
    #pragma unroll
    for (int ks = 0; ks < 16; ks++) {
        float4 t0 = *(const float4*)(wp + ks * 16 + q2 * 8);
        float4 t1 = *(const float4*)(wp + ks * 16 + q2 * 8 + 4);
        bf16x8 f;
        f[0] = (__bf16)t0.x; f[1] = (__bf16)t0.y; f[2] = (__bf16)t0.z; f[3] = (__bf16)t0.w;
        f[4] = (__bf16)t1.x; f[5] = (__bf16)t1.y; f[6] = (__bf16)t1.z; f[7] = (__bf16)t1.w;
        wf[ks] = f;
    }

    float bv[16], bvv = 0.f;
    if (ot < 4) {
        #pragma unroll
        for (int gI = 0; gI < 4; gI++)
            #pragma unroll
            for (int j = 0; j < 4; j++)
                bv[gI * 4 + j] = bias[B0 + gI * 8 + 4 * q2 + j];
    } else {
        bvv = bias[B0 + n31];
    }

    const __bf16* xb = xnb + (size_t)b * 128 * 8192;

    for (int t = 0; t < 4; t++) {
        int nt = nc * 4 + t;
        const __bf16* xg = xb + (size_t)nt * 8192 + q2 * 256 + n31 * 8;
        bf16x8 xf[16];
        #pragma unroll
        for (int ks = 0; ks < 16; ks++) xf[ks] = *(const bf16x8*)(xg + ks * 512);

        f32x16 acc;
        #pragma unroll
        for (int i = 0; i < 16; i++) acc[i] = 0.f;
        if (ot < 4) {
            #pragma unroll
            for (int ks = 0; ks < 16; ks++)
                acc = __builtin_amdgcn_mfma_f32_32x32x16_bf16(wf[ks], xf[ks], acc, 0, 0, 0);
        } else {
            #pragma unroll
            for (int ks = 0; ks < 16; ks++)
                acc = __builtin_amdgcn_mfma_f32_32x32x16_bf16(xf[ks], wf[ks], acc, 0, 0, 0);
        }

        if (ot < 4) {
            int ocb = (ot < 2) ? B0 : (B0 - 256);
            __bf16* dst = (ot < 2) ? q : k;
            bool isq = (ot < 2);
            #pragma unroll
            for (int gI = 0; gI < 4; gI++) {
                bf16x4 pk;
                #pragma unroll
                for (int j = 0; j < 4; j++) {
                    float y = acc[gI * 4 + j] + bv[gI * 4 + j];
                    if (isq) y *= SCALE;
                    pk[j] = (__bf16)y;
                }
                size_t idx = ((((size_t)(b * 128 + nt) * 16 + ((ocb >> 4) + (gI >> 1))) * 2
                               + (gI & 1)) * 32 + n31) * 8 + 4 * q2;
                *(bf16x4*)(dst + idx) = pk;
            }
        } else {
            int ocb = B0 - 512;
            #pragma unroll
            for (int gI = 0; gI < 4; gI++) {
                bf16x4 pk;
                #pragma unroll
                for (int j = 0; j < 4; j++)
                    pk[j] = (__bf16)(acc[gI * 4 + j] + bvv);
                size_t idx = (((((size_t)(b * 128 + nt) * 2 + (gI >> 1)) * 2 + (gI & 1)) * 8
                               + (ocb >> 5)) * 32 + n31) * 8 + 4 * q2;
                *(bf16x4*)(v + idx) = pk;
            }
        }
    }
}

// ---------------------------------------------------------------------------
// Kernel 3 (R5): occupancy-first producer/consumer attention.
// Grid 1024 = b(4) x split(4) x qt(64); block = 64 q-rows x 1024 keys,
// 8 chunks of 128 keys. NO K in LDS: each producer wave owns a DISTINCT
// 32-key slice (kt=wid) of the chunk and reads K global->reg (dup-free,
// L2-resident); Q (all 64 rows) resident in 128 VGPRs. LDS = P ping-pong
// 2x16KB + l = 33KB -> 4 blocks/CU, 32 waves/CU (8/SIMD) — 2x the TLP of
// R4 (the counters showed a stall-bound regime at 16 waves/CU).
// l is block-complete (all 1024 keys of this split) -> consumers normalize
// O in-kernel and store bf16 split-normalized partials; proj blends 4
// planes with weights l_s/sum(l_s). ao traffic unchanged vs R4 (33.5MB).
// ---------------------------------------------------------------------------
__global__ __launch_bounds__(512, 8) void attn_kernel(const __bf16* __restrict__ q,
                                                      const __bf16* __restrict__ k,
                                                      const __bf16* __restrict__ v,
                                                      __bf16* __restrict__ aob,
                                                      float* __restrict__ lpart) {
    __shared__ __align__(16) __bf16 p_lds[2][64 * 128]; // 2 x 16 KB, XOR-swizzled
    __shared__ float l_lds[64];

    int bid   = blockIdx.x;
    int bs    = bid & 15;                    // (b,split): low bits -> XCD spread
    int b     = bs >> 2;
    int split = bs & 3;
    int qt    = bid >> 4;                    // 0..63, 64-row q tile
    int n0    = qt * 64;

    int tid = threadIdx.x;
    int wid = tid >> 6, lane = tid & 63;
    int n31 = lane & 31, q2 = lane >> 5;

    if (tid < 64) l_lds[tid] = 0.f;

    const size_t BSTR = (size_t)N_ * C_;
    const size_t PLANE = (size_t)B_ * C_ * N_;   // ao plane (elements)

    if (wid < 4) {
        // ================= PRODUCER =================
        int kt = wid;                        // distinct 32-key slice of 128-chunk
        // Q: all 64 rows (2 rt tiles) resident, 128 VGPRs.
        const __bf16* qg = q + (size_t)(b * 128 + qt * 2) * 8192
                           + q2 * 256 + n31 * 8;
        bf16x8 qf0[16], qf1[16];
        #pragma unroll
        for (int ks = 0; ks < 16; ks++) {
            qf0[ks] = *(const bf16x8*)(qg + ks * 512);
            qf1[ks] = *(const bf16x8*)(qg + 8192 + ks * 512);
        }
        // K base: key block (32 keys) index = split*32 + ch*4 + kt.
        const __bf16* kbase = k + (size_t)(b * 128 + split * 32 + kt) * 8192
                              + q2 * 256 + n31 * 8;
        float l_acc0 = 0.f, l_acc1 = 0.f;
        int swz = (n31 & 7) << 4;            // same for row n31 and 32+n31

        for (int ch = 0; ch < NCH2; ch++) {
            __syncthreads();                 // P[(ch-2)] fully consumed
            const __bf16* kg = kbase + (size_t)ch * 32768;   // +ch*4 blocks
            f32x16 sa, sb;
            #pragma unroll
            for (int i = 0; i < 16; i++) { sa[i] = 0.f; sb[i] = 0.f; }
            __builtin_amdgcn_s_setprio(1);
            #pragma unroll
            for (int i4 = 0; i4 < 4; i4++) {
                bf16x8 kfr[4];
                #pragma unroll
                for (int j = 0; j < 4; j++)
                    kfr[j] = *(const bf16x8*)(kg + (i4 * 4 + j) * 512);
                #pragma unroll
                for (int j = 0; j < 4; j++) {
                    sa = __builtin_amdgcn_mfma_f32_32x32x16_bf16(kfr[j], qf0[i4 * 4 + j], sa, 0, 0, 0);
                    sb = __builtin_amdgcn_mfma_f32_32x32x16_bf16(kfr[j], qf1[i4 * 4 + j], sb, 0, 0, 0);
                }
            }
            __builtin_amdgcn_s_setprio(0);
            // P write: row stride 256B; keys kt*32 + gI*8 + 4q2 + j.
            char* pbuf = (char*)p_lds[ch & 1];
            #pragma unroll
            for (int gI = 0; gI < 4; gI++) {
                bf16x4 pw0, pw1;
                #pragma unroll
                for (int j = 0; j < 4; j++) {
                    float p0 = __expf(sa[gI * 4 + j]);
                    float p1 = __expf(sb[gI * 4 + j]);
                    l_acc0 += p0; l_acc1 += p1;
                    pw0[j] = (__bf16)p0; pw1[j] = (__bf16)p1;
                }
                int inrow = kt * 64 + gI * 16 + q2 * 8;
                *(bf16x4*)(pbuf + ((n31 * 256 + inrow) ^ swz)) = pw0;
                *(bf16x4*)(pbuf + (((32 + n31) * 256 + inrow) ^ swz)) = pw1;
            }
        }
        // l: combine q2 halves -> lanes 0..31 hold full kt-slice row sums.
        l_acc0 += __shfl_down(l_acc0, 32);
        l_acc1 += __shfl_down(l_acc1, 32);
        if (lane < 32) {
            atomicAdd(&l_lds[lane], l_acc0);
            atomicAdd(&l_lds[32 + lane], l_acc1);
        }
        __syncthreads();                     // final barrier (matches consumer)
        if (tid < 64)                        // wave 0 stores l plane
            lpart[((size_t)split * B_ + b) * N_ + n0 + tid] = l_lds[tid];
    } else {
        // ================= CONSUMER =================
        int cw = wid - 4;                    // owns chans [cw*64, +64)
        const __bf16* vbase = v + (size_t)b * BSTR + (size_t)split * 262144
                              + (size_t)q2 * 2048 + n31 * 8;
        f32x16 o_acc[2][2];                  // [ct][rt]
        #pragma unroll
        for (int ct = 0; ct < 2; ct++)
            #pragma unroll
            for (int rt = 0; rt < 2; rt++)
                #pragma unroll
                for (int i = 0; i < 16; i++) o_acc[ct][rt][i] = 0.f;

        for (int ch = 0; ch < NCH2; ch++) {
            __syncthreads();
            if (ch > 0) {
                int cc = ch - 1;
                // 16 V frags for the 128-key chunk (keys = cc*128 ..).
                bf16x8 vf[2][8];
                #pragma unroll
                for (int ct = 0; ct < 2; ct++)
                    #pragma unroll
                    for (int ks = 0; ks < 8; ks++) {
                        size_t off = (size_t)(cc * 4 + (ks >> 1)) * 8192
                                   + (size_t)(ks & 1) * 4096 + (cw * 2 + ct) * 256;
                        vf[ct][ks] = *(const bf16x8*)(vbase + off);
                    }
                const char* pbuf = (const char*)p_lds[cc & 1];
                __builtin_amdgcn_s_setprio(1);
                #pragma unroll
                for (int rt = 0; rt < 2; rt++) {
                    int prow = rt * 32 + n31;
                    int swz  = (prow & 7) << 4;
                    int pbs  = prow * 256 + q2 * 16;
                    #pragma unroll
                    for (int ks = 0; ks < 8; ks++) {
                        bf16x8 pf = *(const bf16x8*)(pbuf + ((pbs + ks * 32) ^ swz));
                        o_acc[0][rt] = __builtin_amdgcn_mfma_f32_32x32x16_bf16(
                            vf[0][ks], pf, o_acc[0][rt], 0, 0, 0);
                        o_acc[1][rt] = __builtin_amdgcn_mfma_f32_32x32x16_bf16(
                            vf[1][ks], pf, o_acc[1][rt], 0, 0, 0);
                    }
                }
                __builtin_amdgcn_s_setprio(0);
            }
        }
        __syncthreads();                     // final barrier (l_lds complete)
        {   // tail: consume chunk 7 from p_lds[1]
            int cc = NCH2 - 1;
            bf16x8 vf[2][8];
            #pragma unroll
            for (int ct = 0; ct < 2; ct++)
                #pragma unroll
                for (int ks = 0; ks < 8; ks++) {
                    size_t off = (size_t)(cc * 4 + (ks >> 1)) * 8192
                               + (size_t)(ks & 1) * 4096 + (cw * 2 + ct) * 256;
                    vf[ct][ks] = *(const bf16x8*)(vbase + off);
                }
            const char* pbuf = (const char*)p_lds[1];
            __builtin_amdgcn_s_setprio(1);
            #pragma unroll
            for (int rt = 0; rt < 2; rt++) {
                int prow = rt * 32 + n31;
                int swz  = (prow & 7) << 4;
                int pbs  = prow * 256 + q2 * 16;
                #pragma unroll
                for (int ks = 0; ks < 8; ks++) {
                    bf16x8 pf = *(const bf16x8*)(pbuf + ((pbs + ks * 32) ^ swz));
                    o_acc[0][rt] = __builtin_amdgcn_mfma_f32_32x32x16_bf16(
                        vf[0][ks], pf, o_acc[0][rt], 0, 0, 0);
                    o_acc[1][rt] = __builtin_amdgcn_mfma_f32_32x32x16_bf16(
                        vf[1][ks], pf, o_acc[1][rt], 0, 0, 0);
                }
            }
            __builtin_amdgcn_s_setprio(0);
        }
        // Normalize by this block's split-local l, store bf16 partials.
        // Layout per plane (elements): [b][qt][cw][ct][rt][g][q2][n31*4].
        float inv0 = 1.0f / l_lds[n31];
        float inv1 = 1.0f / l_lds[32 + n31];
        __bf16* aop = aob + (size_t)split * PLANE;
        #pragma unroll
        for (int ct = 0; ct < 2; ct++)
            #pragma unroll
            for (int rt = 0; rt < 2; rt++) {
                float inv = rt ? inv1 : inv0;
                #pragma unroll
                for (int g = 0; g < 4; g++) {
                    bf16x4 st;
                    #pragma unroll
                    for (int j = 0; j < 4; j++)
                        st[j] = (__bf16)(o_acc[ct][rt][g * 4 + j] * inv);
                    size_t idx = ((((((size_t)(b * 64 + qt) * 4 + cw) * 2 + ct) * 2 + rt)
                                   * 4 + g) * 2 + q2) * 128 + n31 * 4;
                    *(bf16x4*)(aop + idx) = st;
                }
            }
    }
}

// ---------------------------------------------------------------------------
// Kernel 4: out projection. Blends 4 split-normalized bf16 partials with
// weights w_s = l_s / sum(l_s), then bf16 MFMA + bias + residual.
// ---------------------------------------------------------------------------
__global__ __launch_bounds__(256) void proj_kernel(const __bf16* __restrict__ aob,
                                                   const float* __restrict__ lpart,
                                                   const float* __restrict__ W2,
                                                   const float* __restrict__ bias,
                                                   const float* __restrict__ x,
                                                   float* __restrict__ out) {
    int b = blockIdx.z, ot = blockIdx.y, nc = blockIdx.x;
    int tid = threadIdx.x, wv = tid >> 6, lane = tid & 63;
    int n31 = lane & 31, q2 = lane >> 5;
    int B0 = ot * 128 + wv * 32;
    const size_t PLANE = (size_t)B_ * C_ * N_;

    bf16x8 wf[16];
    const float* wp = W2 + (size_t)(B0 + n31) * C_;
    #pragma unroll
    for (int ks = 0; ks < 16; ks++) {
        float4 t0 = *(const float4*)(wp + ks * 16 + q2 * 8);
        float4 t1 = *(const float4*)(wp + ks * 16 + q2 * 8 + 4);
        bf16x8 f;
        f[0] = (__bf16)t0.x; f[1] = (__bf16)t0.y; f[2] = (__bf16)t0.z; f[3] = (__bf16)t0.w;
        f[4] = (__bf16)t1.x; f[5] = (__bf16)t1.y; f[6] = (__bf16)t1.z; f[7] = (__bf16)t1.w;
        wf[ks] = f;
    }
    float bv[16];
    #pragma unroll
    for (int r = 0; r < 16; r++) bv[r] = bias[B0 + (r & 3) + 8 * (r >> 2) + 4 * q2];

    for (int t = 0; t < 4; t++) {
        int nt = nc * 4 + t;                  // 32-row tile, 0..127
        int qt = nt >> 1, rtile = nt & 1;
        int n = nt * 32 + n31;
        size_t ln = (size_t)b * N_ + n;
        float w0 = lpart[ln];
        float w1 = lpart[(size_t)B_ * N_ + ln];
        float w2 = lpart[2 * (size_t)B_ * N_ + ln];
        float w3 = lpart[3 * (size_t)B_ * N_ + ln];
        float invt = 1.0f / (w0 + w1 + w2 + w3);
        w0 *= invt; w1 *= invt; w2 *= invt; w3 *= invt;

        bf16x8 xf[16];
        #pragma unroll
        for (int ks = 0; ks < 16; ks++) {
            int oct = ks * 2 + q2;            // chan octet 0..31
            int cw = oct >> 3, ct = (oct >> 2) & 1, ga = oct & 3;
            size_t base = ((((((size_t)(b * 64 + qt) * 4 + cw) * 2 + ct) * 2 + rtile)
                            * 4 + ga) * 2) * 128 + n31 * 4;
            float a[8];
            #pragma unroll
            for (int j = 0; j < 8; j++) a[j] = 0.f;
            #pragma unroll
            for (int s = 0; s < 4; s++) {
                float ws = (s == 0) ? w0 : (s == 1) ? w1 : (s == 2) ? w2 : w3;
                bf16x4 p0 = *(const bf16x4*)(aob + s * PLANE + base);
                bf16x4 p1 = *(const bf16x4*)(aob + s * PLANE + base + 128);
                #pragma unroll
                for (int j = 0; j < 4; j++) {
                    a[j]     += ws * (float)p0[j];
                    a[4 + j] += ws * (float)p1[j];
                }
            }
            bf16x8 f;
            #pragma unroll
            for (int j = 0; j < 8; j++) f[j] = (__bf16)a[j];
            xf[ks] = f;
        }

        f32x16 acc;
        #pragma unroll
        for (int i = 0; i < 16; i++) acc[i] = 0.f;
        #pragma unroll
        for (int ks = 0; ks < 16; ks++)
            acc = __builtin_amdgcn_mfma_f32_32x32x16_bf16(wf[ks], xf[ks], acc, 0, 0, 0);

        #pragma unroll
        for (int r = 0; r < 16; r++) {
            int o = B0 + (r & 3) + 8 * (r >> 2) + 4 * q2;
            size_t idx = ((size_t)(b * C_ + o)) * N_ + nt * 32 + n31;
            out[idx] = acc[r] + bv[r] + x[idx];
        }
    }
}

// ---------------------------------------------------------------------------
extern "C" void kernel_launch(void* const* d_in, const int* in_sizes, int n_in,
                              void* d_out, int out_size, void* d_ws, size_t ws_size,
                              hipStream_t stream) {
    const float* x     = (const float*)d_in[0];
    const float* gn_w  = (const float*)d_in[1];
    const float* gn_b  = (const float*)d_in[2];
    const float* qkv_w = (const float*)d_in[3];
    const float* qkv_b = (const float*)d_in[4];
    const float* out_w = (const float*)d_in[5];
    const float* out_b = (const float*)d_in[6];
    float* out = (float*)d_out;

    const size_t SZ = (size_t)B_ * C_ * N_;       // 4,194,304 elements
    char* base = (char*)d_ws;
    __bf16* aob = (__bf16*)base;                  // 4 bf16 planes = 33.5 MB
    __bf16* xnb = (__bf16*)base;                  // aliases aob (dead by attn)
    __bf16* qb  = (__bf16*)(base + 2 * SZ * 4);   // 8.39 MB each
    __bf16* kb  = qb + SZ;
    __bf16* vb  = kb + SZ;
    float*  lpart = (float*)(base + 2 * SZ * 4 + 3 * SZ * 2);  // [4][B][N] fp32
    float*  part  = lpart + 4 * (size_t)B_ * N_;  // [512][2] GN partials

    gn_stats_kernel<<<dim3(512), 256, 0, stream>>>(x, part);
    gn_apply_kernel<<<dim3(2048), 256, 0, stream>>>(x, gn_w, gn_b, part, xnb);
    qkv_kernel<<<dim3(32, 6, B_), 256, 0, stream>>>(xnb, qkv_w, qkv_b, qb, kb, vb);
    attn_kernel<<<dim3(1024), 512, 0, stream>>>(qb, kb, vb, aob, lpart);
    proj_kernel<<<dim3(32, 2, B_), 256, 0, stream>>>(aob, lpart, out_w, out_b, x, out);
}

// Round 6
// 212.656 us; speedup vs baseline: 4.5490x; 4.5490x over previous
//
#include <hip/hip_runtime.h>
#include <math.h>

#define B_   4
#define C_   256
#define G_   32
#define CPG  8                 // channels per group
#define N_   4096              // H*W
#define NPG  (CPG * N_)        // 32768 elements per group
#define EPS  1e-5f
#define SCALE 0.0625f          // C^-0.5 = 1/16
#define NCH  32                // key chunks of 64 per (split) half

typedef __attribute__((ext_vector_type(8)))  __bf16 bf16x8;
typedef __attribute__((ext_vector_type(4)))  __bf16 bf16x4;
typedef __attribute__((ext_vector_type(16))) float  f32x16;

// ---------------------------------------------------------------------------
// Kernel 1a: GroupNorm partial sums (unchanged).
// ---------------------------------------------------------------------------
__global__ __launch_bounds__(256) void gn_stats_kernel(const float* __restrict__ x,
                                                       float* __restrict__ part) {
    int bid = blockIdx.x;
    int bg = bid >> 2, seg = bid & 3;
    const float4* xp4 = (const float4*)(x + (size_t)bg * NPG) + seg * 2048;
    int tid = threadIdx.x;

    float s = 0.f, ss = 0.f;
    for (int i = tid; i < 2048; i += 256) {
        float4 t = xp4[i];
        s  += t.x + t.y + t.z + t.w;
        ss += t.x * t.x + t.y * t.y + t.z * t.z + t.w * t.w;
    }
    #pragma unroll
    for (int off = 32; off; off >>= 1) {
        s  += __shfl_xor(s, off, 64);
        ss += __shfl_xor(ss, off, 64);
    }
    __shared__ float rs[2][4];
    int wave = tid >> 6, lane = tid & 63;
    if (lane == 0) { rs[0][wave] = s; rs[1][wave] = ss; }
    __syncthreads();
    if (tid == 0) {
        part[bid * 2]     = rs[0][0] + rs[0][1] + rs[0][2] + rs[0][3];
        part[bid * 2 + 1] = rs[1][0] + rs[1][1] + rs[1][2] + rs[1][3];
    }
}

// ---------------------------------------------------------------------------
// Kernel 1b: GroupNorm apply -> bf16 frag-interleaved (unchanged).
// ---------------------------------------------------------------------------
__global__ __launch_bounds__(256) void gn_apply_kernel(const float* __restrict__ x,
                                                       const float* __restrict__ w,
                                                       const float* __restrict__ bia,
                                                       const float* __restrict__ part,
                                                       __bf16* __restrict__ xnb) {
    int bid = blockIdx.x;
    int bg = bid >> 4, seg = bid & 15;
    int b = bg >> 5, g = bg & 31;
    float s  = part[(bg * 4 + 0) * 2] + part[(bg * 4 + 1) * 2]
             + part[(bg * 4 + 2) * 2] + part[(bg * 4 + 3) * 2];
    float ss = part[(bg * 4 + 0) * 2 + 1] + part[(bg * 4 + 1) * 2 + 1]
             + part[(bg * 4 + 2) * 2 + 1] + part[(bg * 4 + 3) * 2 + 1];
    float mean = s / (float)NPG;
    float var  = ss / (float)NPG - mean * mean;
    float rstd = rsqrtf(var + EPS);

    const float* xp = x + (size_t)bg * NPG;
    int n = seg * 256 + threadIdx.x;

    bf16x8 pk;
    #pragma unroll
    for (int cc = 0; cc < 8; cc++) {
        float sc = rstd * w[g * CPG + cc];
        float sh = bia[g * CPG + cc] - mean * sc;
        pk[cc] = (__bf16)(xp[(size_t)cc * N_ + n] * sc + sh);
    }
    size_t idx = ((((size_t)(b * 128 + (n >> 5)) * 16 + (g >> 1)) * 2 + (g & 1))
                  * 32 + (n & 31)) * 8;
    *(bf16x8*)(xnb + idx) = pk;
}

// ---------------------------------------------------------------------------
// Kernel 2: QKV projection, bf16 MFMA (unchanged).
// ---------------------------------------------------------------------------
__global__ __launch_bounds__(256) void qkv_kernel(const __bf16* __restrict__ xnb,
                                                  const float* __restrict__ W,
                                                  const float* __restrict__ bias,
                                                  __bf16* __restrict__ q,
                                                  __bf16* __restrict__ k,
                                                  __bf16* __restrict__ v) {
    int b = blockIdx.z, ot = blockIdx.y, nc = blockIdx.x;
    int tid = threadIdx.x, wv = tid >> 6, lane = tid & 63;
    int n31 = lane & 31, q2 = lane >> 5;
    int B0 = ot * 128 + wv * 32;

    bf16x8 wf[16];
    const float* wp = W + (size_t)(B0 + n31) * C_;
    #pragma unroll
    for (int ks = 0; ks < 16; ks++) {
        float4 t0 = *(const float4*)(wp + ks * 16 + q2 * 8);
        float4 t1 = *(const float4*)(wp + ks * 16 + q2 * 8 + 4);
        bf16x8 f;
        f[0] = (__bf16)t0.x; f[1] = (__bf16)t0.y; f[2] = (__bf16)t0.z; f[3] = (__bf16)t0.w;
        f[4] = (__bf16)t1.x; f[5] = (__bf16)t1.y; f[6] = (__bf16)t1.z; f[7] = (__bf16)t1.w;
        wf[ks] = f;
    }

    float bv[16], bvv = 0.f;
    if (ot < 4) {
        #pragma unroll
        for (int gI = 0; gI < 4; gI++)
            #pragma unroll
            for (int j = 0; j < 4; j++)
                bv[gI * 4 + j] = bias[B0 + gI * 8 + 4 * q2 + j];
    } else {
        bvv = bias[B0 + n31];
    }

    const __bf16* xb = xnb + (size_t)b * 128 * 8192;

    for (int t = 0; t < 4; t++) {
        int nt = nc * 4 + t;
        const __bf16* xg = xb + (size_t)nt * 8192 + q2 * 256 + n31 * 8;
        bf16x8 xf[16];
        #pragma unroll
        for (int ks = 0; ks < 16; ks++) xf[ks] = *(const bf16x8*)(xg + ks * 512);

        f32x16 acc;
        #pragma unroll
        for (int i = 0; i < 16; i++) acc[i] = 0.f;
        if (ot < 4) {
            #pragma unroll
            for (int ks = 0; ks < 16; ks++)
                acc = __builtin_amdgcn_mfma_f32_32x32x16_bf16(wf[ks], xf[ks], acc, 0, 0, 0);
        } else {
            #pragma unroll
            for (int ks = 0; ks < 16; ks++)
                acc = __builtin_amdgcn_mfma_f32_32x32x16_bf16(xf[ks], wf[ks], acc, 0, 0, 0);
        }

        if (ot < 4) {
            int ocb = (ot < 2) ? B0 : (B0 - 256);
            __bf16* dst = (ot < 2) ? q : k;
            bool isq = (ot < 2);
            #pragma unroll
            for (int gI = 0; gI < 4; gI++) {
                bf16x4 pk;
                #pragma unroll
                for (int j = 0; j < 4; j++) {
                    float y = acc[gI * 4 + j] + bv[gI * 4 + j];
                    if (isq) y *= SCALE;
                    pk[j] = (__bf16)y;
                }
                size_t idx = ((((size_t)(b * 128 + nt) * 16 + ((ocb >> 4) + (gI >> 1))) * 2
                               + (gI & 1)) * 32 + n31) * 8 + 4 * q2;
                *(bf16x4*)(dst + idx) = pk;
            }
        } else {
            int ocb = B0 - 512;
            #pragma unroll
            for (int gI = 0; gI < 4; gI++) {
                bf16x4 pk;
                #pragma unroll
                for (int j = 0; j < 4; j++)
                    pk[j] = (__bf16)(acc[gI * 4 + j] + bvv);
                size_t idx = (((((size_t)(b * 128 + nt) * 2 + (gI >> 1)) * 2 + (gI & 1)) * 8
                               + (ocb >> 5)) * 32 + n31) * 8 + 4 * q2;
                *(bf16x4*)(v + idx) = pk;
            }
        }
    }
}

// ---------------------------------------------------------------------------
// Kernel 3 (R6 = R4 structure + in-LDS l + normalized bf16 output).
// Producer/consumer attention, 2 blocks/CU (register-bound: 64 VGPR + 64
// AGPR = 128 combined -> 16 waves/CU; LDS 80 KB binds at the same point).
// K staged via async global_load_lds double-buffer (one chunk ahead);
// producer K-reads ds_read_b128; Q in registers; P XOR-swizzled in LDS;
// consumer V loads in-phase; setprio around MFMA clusters. l reduced via
// LDS atomics (R0 pattern) before the tail barrier; consumers normalize
// and store bf16 split-partials (halves attn WRITE_SIZE and proj reads).
// ---------------------------------------------------------------------------
__device__ __forceinline__ void stage16(const __bf16* g, __bf16* l) {
    __builtin_amdgcn_global_load_lds(
        (const __attribute__((address_space(1))) unsigned int*)g,
        (__attribute__((address_space(3))) unsigned int*)l, 16, 0, 0);
}

__global__ __launch_bounds__(512, 4) void attn_kernel(const __bf16* __restrict__ q,
                                                      const __bf16* __restrict__ k,
                                                      const __bf16* __restrict__ v,
                                                      __bf16* __restrict__ aob,
                                                      float* __restrict__ lpart) {
    __shared__ __align__(16) __bf16 k_lds[2][16384];   // 2 x 32 KB double buffer
    __shared__ __align__(16) __bf16 p_lds[2][64 * 64]; // 2 x 8 KB, XOR-swizzled
    __shared__ float l_lds[64];

    int bid   = blockIdx.x;
    int xcd   = bid & 7;
    int b     = xcd >> 1;
    int split = xcd & 1;
    int qt    = bid >> 3;                    // 0..63, 64-row q tile
    int n0    = qt * 64;

    int tid = threadIdx.x;
    int wid = tid >> 6, lane = tid & 63;
    int n31 = lane & 31, q2 = lane >> 5;

    if (tid < 64) l_lds[tid] = 0.f;

    const size_t BSTR = (size_t)N_ * C_;
    const size_t PLANE = (size_t)B_ * C_ * N_;   // elements per split plane
    // K chunk ch occupies contiguous shorts [ch*16384, +16384) of this
    // block's key range: linear global->LDS copy.
    const __bf16* kgbase = k + (size_t)(b * 128 + split * 64) * 8192
                           + wid * 2048 + lane * 8;

    // prologue: stage chunk 0 into buf 0 (each wave: 4 x 1 KB segments)
    {
        __bf16* l = (__bf16*)k_lds[0] + wid * 2048;
        #pragma unroll
        for (int i = 0; i < 4; i++)
            stage16(kgbase + i * 512, l + i * 512);
    }

    if (wid < 4) {
        // ================= PRODUCER =================
        int kt = wid & 1;                    // 32-key slice within chunk
        int rt = wid >> 1;                   // 32-row tile within 64 rows
        const __bf16* qg = q + (size_t)(b * 128 + qt * 2 + rt) * 8192
                           + q2 * 256 + n31 * 8;
        bf16x8 qf[16];
        #pragma unroll
        for (int ks = 0; ks < 16; ks++) qf[ks] = *(const bf16x8*)(qg + ks * 512);

        float l_acc = 0.f;
        int prow = rt * 32 + n31;
        int swz  = (prow & 7) << 4;
        int klo  = kt * 8192 + q2 * 256 + n31 * 8;

        for (int ch = 0; ch < NCH; ch++) {
            __syncthreads();                 // K[ch] staged, P[(ch-1)] consumed
            if (ch < NCH - 1) {              // stage K[ch+1] into other buffer
                const __bf16* g = kgbase + (size_t)(ch + 1) * 16384;
                __bf16* l = (__bf16*)k_lds[(ch + 1) & 1] + wid * 2048;
                #pragma unroll
                for (int i = 0; i < 4; i++)
                    stage16(g + i * 512, l + i * 512);
            }
            const __bf16* kl = (const __bf16*)k_lds[ch & 1] + klo;
            f32x16 sa, sb;
            #pragma unroll
            for (int i = 0; i < 16; i++) { sa[i] = 0.f; sb[i] = 0.f; }
            __builtin_amdgcn_s_setprio(1);
            #pragma unroll
            for (int i = 0; i < 8; i++) {    // two independent 8-deep chains
                bf16x8 ka = *(const bf16x8*)(kl + i * 512);
                bf16x8 kb = *(const bf16x8*)(kl + (i + 8) * 512);
                sa = __builtin_amdgcn_mfma_f32_32x32x16_bf16(ka, qf[i], sa, 0, 0, 0);
                sb = __builtin_amdgcn_mfma_f32_32x32x16_bf16(kb, qf[i + 8], sb, 0, 0, 0);
            }
            __builtin_amdgcn_s_setprio(0);
            char* pbuf = (char*)p_lds[ch & 1];
            #pragma unroll
            for (int gI = 0; gI < 4; gI++) {
                bf16x4 pw;
                #pragma unroll
                for (int j = 0; j < 4; j++) {
                    float p = __expf(sa[gI * 4 + j] + sb[gI * 4 + j]);
                    l_acc += p;
                    pw[j] = (__bf16)p;
                }
                int off = prow * 128 + kt * 64 + 16 * gI + 8 * q2;
                *(bf16x4*)(pbuf + (off ^ swz)) = pw;
            }
        }
        // l: combine q2 halves, accumulate both kt slices in LDS.
        l_acc += __shfl_down(l_acc, 32);
        if (lane < 32) atomicAdd(&l_lds[rt * 32 + lane], l_acc);
        __syncthreads();                     // pairs with consumer tail barrier
        if (tid < 64)                        // wave 0 stores the l plane
            lpart[((size_t)split * B_ + b) * N_ + n0 + tid] = l_lds[tid];
    } else {
        // ================= CONSUMER =================
        int cw = wid - 4;                    // owns chans [cw*64, +64)
        const __bf16* vbase = v + (size_t)b * BSTR + (size_t)split * 524288
                              + (size_t)q2 * 2048 + n31 * 8;
        f32x16 o_acc[2][2];                  // [ct][rt]
        #pragma unroll
        for (int ct = 0; ct < 2; ct++)
            #pragma unroll
            for (int rt = 0; rt < 2; rt++)
                #pragma unroll
                for (int i = 0; i < 16; i++) o_acc[ct][rt][i] = 0.f;

        for (int ch = 0; ch < NCH; ch++) {
            __syncthreads();
            if (ch < NCH - 1) {              // stage K[ch+1] share
                const __bf16* g = kgbase + (size_t)(ch + 1) * 16384;
                __bf16* l = (__bf16*)k_lds[(ch + 1) & 1] + wid * 2048;
                #pragma unroll
                for (int i = 0; i < 4; i++)
                    stage16(g + i * 512, l + i * 512);
            }
            if (ch > 0) {
                int cc = ch - 1;
                // V loads issued at phase start; covered by pf reads + MFMAs.
                bf16x8 vf[2][4];
                #pragma unroll
                for (int ct = 0; ct < 2; ct++)
                    #pragma unroll
                    for (int ks4 = 0; ks4 < 4; ks4++) {
                        size_t off = (size_t)(cc * 2 + (ks4 >> 1)) * 8192
                                   + (size_t)(ks4 & 1) * 4096 + (cw * 2 + ct) * 256;
                        vf[ct][ks4] = *(const bf16x8*)(vbase + off);
                    }
                const char* pbuf = (const char*)p_lds[cc & 1];
                __builtin_amdgcn_s_setprio(1);
                #pragma unroll
                for (int rt = 0; rt < 2; rt++) {
                    int prow = rt * 32 + n31;
                    int swz  = (prow & 7) << 4;
                    int pbs  = prow * 128 + q2 * 16;
                    #pragma unroll
                    for (int ks4 = 0; ks4 < 4; ks4++) {
                        bf16x8 pf = *(const bf16x8*)(pbuf + ((pbs + ks4 * 32) ^ swz));
                        o_acc[0][rt] = __builtin_amdgcn_mfma_f32_32x32x16_bf16(
                            vf[0][ks4], pf, o_acc[0][rt], 0, 0, 0);
                        o_acc[1][rt] = __builtin_amdgcn_mfma_f32_32x32x16_bf16(
                            vf[1][ks4], pf, o_acc[1][rt], 0, 0, 0);
                    }
                }
                __builtin_amdgcn_s_setprio(0);
            }
        }
        __syncthreads();                     // pairs with producer tail barrier
        {   // tail: consume chunk 31 from p_lds[1]
            int cc = NCH - 1;
            bf16x8 vf[2][4];
            #pragma unroll
            for (int ct = 0; ct < 2; ct++)
                #pragma unroll
                for (int ks4 = 0; ks4 < 4; ks4++) {
                    size_t off = (size_t)(cc * 2 + (ks4 >> 1)) * 8192
                               + (size_t)(ks4 & 1) * 4096 + (cw * 2 + ct) * 256;
                    vf[ct][ks4] = *(const bf16x8*)(vbase + off);
                }
            const char* pbuf = (const char*)p_lds[1];
            __builtin_amdgcn_s_setprio(1);
            #pragma unroll
            for (int rt = 0; rt < 2; rt++) {
                int prow = rt * 32 + n31;
                int swz  = (prow & 7) << 4;
                int pbs  = prow * 128 + q2 * 16;
                #pragma unroll
                for (int ks4 = 0; ks4 < 4; ks4++) {
                    bf16x8 pf = *(const bf16x8*)(pbuf + ((pbs + ks4 * 32) ^ swz));
                    o_acc[0][rt] = __builtin_amdgcn_mfma_f32_32x32x16_bf16(
                        vf[0][ks4], pf, o_acc[0][rt], 0, 0, 0);
                    o_acc[1][rt] = __builtin_amdgcn_mfma_f32_32x32x16_bf16(
                        vf[1][ks4], pf, o_acc[1][rt], 0, 0, 0);
                }
            }
            __builtin_amdgcn_s_setprio(0);
        }
        // Normalize by split-local l, store bf16 partials (plane per split).
        // Layout: [b][qt][cw][ct][rt][g][q2][n31*4] — coalesced.
        float inv0 = 1.0f / l_lds[n31];
        float inv1 = 1.0f / l_lds[32 + n31];
        __bf16* aop = aob + (size_t)split * PLANE;
        #pragma unroll
        for (int ct = 0; ct < 2; ct++)
            #pragma unroll
            for (int rt = 0; rt < 2; rt++) {
                float inv = rt ? inv1 : inv0;
                #pragma unroll
                for (int g = 0; g < 4; g++) {
                    bf16x4 st;
                    #pragma unroll
                    for (int j = 0; j < 4; j++)
                        st[j] = (__bf16)(o_acc[ct][rt][g * 4 + j] * inv);
                    size_t idx = ((((((size_t)(b * 64 + qt) * 4 + cw) * 2 + ct) * 2 + rt)
                                   * 4 + g) * 2 + q2) * 128 + n31 * 4;
                    *(bf16x4*)(aop + idx) = st;
                }
            }
    }
}

// ---------------------------------------------------------------------------
// Kernel 4: out projection. Blends 2 split-normalized bf16 planes with
// weights l_s/(l0+l1), then bf16 MFMA + bias + residual.
// ---------------------------------------------------------------------------
__global__ __launch_bounds__(256) void proj_kernel(const __bf16* __restrict__ aob,
                                                   const float* __restrict__ lpart,
                                                   const float* __restrict__ W2,
                                                   const float* __restrict__ bias,
                                                   const float* __restrict__ x,
                                                   float* __restrict__ out) {
    int b = blockIdx.z, ot = blockIdx.y, nc = blockIdx.x;
    int tid = threadIdx.x, wv = tid >> 6, lane = tid & 63;
    int n31 = lane & 31, q2 = lane >> 5;
    int B0 = ot * 128 + wv * 32;
    const size_t BN = (size_t)B_ * N_;
    const size_t PLANE = (size_t)B_ * C_ * N_;

    bf16x8 wf[16];
    const float* wp = W2 + (size_t)(B0 + n31) * C_;
    #pragma unroll
    for (int ks = 0; ks < 16; ks++) {
        float4 t0 = *(const float4*)(wp + ks * 16 + q2 * 8);
        float4 t1 = *(const float4*)(wp + ks * 16 + q2 * 8 + 4);
        bf16x8 f;
        f[0] = (__bf16)t0.x; f[1] = (__bf16)t0.y; f[2] = (__bf16)t0.z; f[3] = (__bf16)t0.w;
        f[4] = (__bf16)t1.x; f[5] = (__bf16)t1.y; f[6] = (__bf16)t1.z; f[7] = (__bf16)t1.w;
        wf[ks] = f;
    }
    float bv[16];
    #pragma unroll
    for (int r = 0; r < 16; r++) bv[r] = bias[B0 + (r & 3) + 8 * (r >> 2) + 4 * q2];

    for (int t = 0; t < 4; t++) {
        int nt = nc * 4 + t;                  // 32-row tile, 0..127
        int qt = nt >> 1, rtile = nt & 1;
        int n = nt * 32 + n31;
        size_t ln = (size_t)b * N_ + n;
        float l0v = lpart[ln];
        float l1v = lpart[BN + ln];
        float invt = 1.0f / (l0v + l1v);
        float w0 = l0v * invt, w1 = l1v * invt;

        bf16x8 xf[16];
        #pragma unroll
        for (int ks = 0; ks < 16; ks++) {
            int oct = ks * 2 + q2;            // chan octet 0..31
            int cw = oct >> 3, ct = (oct >> 2) & 1, ga = oct & 3;
            size_t base = ((((((size_t)(b * 64 + qt) * 4 + cw) * 2 + ct) * 2 + rtile)
                            * 4 + ga) * 2) * 128 + n31 * 4;
            bf16x4 a0 = *(const bf16x4*)(aob + base);
            bf16x4 b0 = *(const bf16x4*)(aob + base + 128);
            bf16x4 a1 = *(const bf16x4*)(aob + PLANE + base);
            bf16x4 b1 = *(const bf16x4*)(aob + PLANE + base + 128);
            bf16x8 f;
            #pragma unroll
            for (int j = 0; j < 4; j++) {
                f[j]     = (__bf16)(w0 * (float)a0[j] + w1 * (float)a1[j]);
                f[4 + j] = (__bf16)(w0 * (float)b0[j] + w1 * (float)b1[j]);
            }
            xf[ks] = f;
        }

        f32x16 acc;
        #pragma unroll
        for (int i = 0; i < 16; i++) acc[i] = 0.f;
        #pragma unroll
        for (int ks = 0; ks < 16; ks++)
            acc = __builtin_amdgcn_mfma_f32_32x32x16_bf16(wf[ks], xf[ks], acc, 0, 0, 0);

        #pragma unroll
        for (int r = 0; r < 16; r++) {
            int o = B0 + (r & 3) + 8 * (r >> 2) + 4 * q2;
            size_t idx = ((size_t)(b * C_ + o)) * N_ + nt * 32 + n31;
            out[idx] = acc[r] + bv[r] + x[idx];
        }
    }
}

// ---------------------------------------------------------------------------
extern "C" void kernel_launch(void* const* d_in, const int* in_sizes, int n_in,
                              void* d_out, int out_size, void* d_ws, size_t ws_size,
                              hipStream_t stream) {
    const float* x     = (const float*)d_in[0];
    const float* gn_w  = (const float*)d_in[1];
    const float* gn_b  = (const float*)d_in[2];
    const float* qkv_w = (const float*)d_in[3];
    const float* qkv_b = (const float*)d_in[4];
    const float* out_w = (const float*)d_in[5];
    const float* out_b = (const float*)d_in[6];
    float* out = (float*)d_out;

    const size_t SZ = (size_t)B_ * C_ * N_;       // 4,194,304 elements
    char* base = (char*)d_ws;
    __bf16* aob = (__bf16*)base;                  // 2 bf16 planes = 16.8 MB
    __bf16* xnb = (__bf16*)base;                  // aliases aob (dead by attn)
    __bf16* qb  = (__bf16*)(base + 2 * SZ * 4);   // 8.39 MB each
    __bf16* kb  = qb + SZ;
    __bf16* vb  = kb + SZ;
    float*  lpart = (float*)(base + 2 * SZ * 4 + 3 * SZ * 2);  // [2][B][N] fp32
    float*  part  = lpart + 2 * (size_t)B_ * N_;  // [512][2] GN partials

    gn_stats_kernel<<<dim3(512), 256, 0, stream>>>(x, part);
    gn_apply_kernel<<<dim3(2048), 256, 0, stream>>>(x, gn_w, gn_b, part, xnb);
    qkv_kernel<<<dim3(32, 6, B_), 256, 0, stream>>>(xnb, qkv_w, qkv_b, qb, kb, vb);
    attn_kernel<<<dim3(512), 512, 0, stream>>>(qb, kb, vb, aob, lpart);
    proj_kernel<<<dim3(32, 2, B_), 256, 0, stream>>>(aob, lpart, out_w, out_b, x, out);
}

// Round 7
// 209.670 us; speedup vs baseline: 4.6137x; 1.0142x over previous
//
#include <hip/hip_runtime.h>
#include <math.h>

#define B_   4
#define C_   256
#define G_   32
#define CPG  8                 // channels per group
#define N_   4096              // H*W
#define NPG  (CPG * N_)        // 32768 elements per group
#define EPS  1e-5f
#define SCALE 0.0625f          // C^-0.5 = 1/16
#define NCH  32                // key chunks of 64 per (split) half

typedef __attribute__((ext_vector_type(8)))  __bf16 bf16x8;
typedef __attribute__((ext_vector_type(4)))  __bf16 bf16x4;
typedef __attribute__((ext_vector_type(16))) float  f32x16;

// ---------------------------------------------------------------------------
// Kernel 1a: GroupNorm partial sums (unchanged).
// ---------------------------------------------------------------------------
__global__ __launch_bounds__(256) void gn_stats_kernel(const float* __restrict__ x,
                                                       float* __restrict__ part) {
    int bid = blockIdx.x;
    int bg = bid >> 2, seg = bid & 3;
    const float4* xp4 = (const float4*)(x + (size_t)bg * NPG) + seg * 2048;
    int tid = threadIdx.x;

    float s = 0.f, ss = 0.f;
    for (int i = tid; i < 2048; i += 256) {
        float4 t = xp4[i];
        s  += t.x + t.y + t.z + t.w;
        ss += t.x * t.x + t.y * t.y + t.z * t.z + t.w * t.w;
    }
    #pragma unroll
    for (int off = 32; off; off >>= 1) {
        s  += __shfl_xor(s, off, 64);
        ss += __shfl_xor(ss, off, 64);
    }
    __shared__ float rs[2][4];
    int wave = tid >> 6, lane = tid & 63;
    if (lane == 0) { rs[0][wave] = s; rs[1][wave] = ss; }
    __syncthreads();
    if (tid == 0) {
        part[bid * 2]     = rs[0][0] + rs[0][1] + rs[0][2] + rs[0][3];
        part[bid * 2 + 1] = rs[1][0] + rs[1][1] + rs[1][2] + rs[1][3];
    }
}

// ---------------------------------------------------------------------------
// Kernel 1b: GroupNorm apply -> bf16 frag-interleaved (unchanged).
// ---------------------------------------------------------------------------
__global__ __launch_bounds__(256) void gn_apply_kernel(const float* __restrict__ x,
                                                       const float* __restrict__ w,
                                                       const float* __restrict__ bia,
                                                       const float* __restrict__ part,
                                                       __bf16* __restrict__ xnb) {
    int bid = blockIdx.x;
    int bg = bid >> 4, seg = bid & 15;
    int b = bg >> 5, g = bg & 31;
    float s  = part[(bg * 4 + 0) * 2] + part[(bg * 4 + 1) * 2]
             + part[(bg * 4 + 2) * 2] + part[(bg * 4 + 3) * 2];
    float ss = part[(bg * 4 + 0) * 2 + 1] + part[(bg * 4 + 1) * 2 + 1]
             + part[(bg * 4 + 2) * 2 + 1] + part[(bg * 4 + 3) * 2 + 1];
    float mean = s / (float)NPG;
    float var  = ss / (float)NPG - mean * mean;
    float rstd = rsqrtf(var + EPS);

    const float* xp = x + (size_t)bg * NPG;
    int n = seg * 256 + threadIdx.x;

    bf16x8 pk;
    #pragma unroll
    for (int cc = 0; cc < 8; cc++) {
        float sc = rstd * w[g * CPG + cc];
        float sh = bia[g * CPG + cc] - mean * sc;
        pk[cc] = (__bf16)(xp[(size_t)cc * N_ + n] * sc + sh);
    }
    size_t idx = ((((size_t)(b * 128 + (n >> 5)) * 16 + (g >> 1)) * 2 + (g & 1))
                  * 32 + (n & 31)) * 8;
    *(bf16x8*)(xnb + idx) = pk;
}

// ---------------------------------------------------------------------------
// Kernel 2: QKV projection, bf16 MFMA (unchanged).
// ---------------------------------------------------------------------------
__global__ __launch_bounds__(256) void qkv_kernel(const __bf16* __restrict__ xnb,
                                                  const float* __restrict__ W,
                                                  const float* __restrict__ bias,
                                                  __bf16* __restrict__ q,
                                                  __bf16* __restrict__ k,
                                                  __bf16* __restrict__ v) {
    int b = blockIdx.z, ot = blockIdx.y, nc = blockIdx.x;
    int tid = threadIdx.x, wv = tid >> 6, lane = tid & 63;
    int n31 = lane & 31, q2 = lane >> 5;
    int B0 = ot * 128 + wv * 32;

    bf16x8 wf[16];
    const float* wp = W + (size_t)(B0 + n31) * C_;
    #pragma unroll
    for (int ks = 0; ks < 16; ks++) {
        float4 t0 = *(const float4*)(wp + ks * 16 + q2 * 8);
        float4 t1 = *(const float4*)(wp + ks * 16 + q2 * 8 + 4);
        bf16x8 f;
        f[0] = (__bf16)t0.x; f[1] = (__bf16)t0.y; f[2] = (__bf16)t0.z; f[3] = (__bf16)t0.w;
        f[4] = (__bf16)t1.x; f[5] = (__bf16)t1.y; f[6] = (__bf16)t1.z; f[7] = (__bf16)t1.w;
        wf[ks] = f;
    }

    float bv[16], bvv = 0.f;
    if (ot < 4) {
        #pragma unroll
        for (int gI = 0; gI < 4; gI++)
            #pragma unroll
            for (int j = 0; j < 4; j++)
                bv[gI * 4 + j] = bias[B0 + gI * 8 + 4 * q2 + j];
    } else {
        bvv = bias[B0 + n31];
    }

    const __bf16* xb = xnb + (size_t)b * 128 * 8192;

    for (int t = 0; t < 4; t++) {
        int nt = nc * 4 + t;
        const __bf16* xg = xb + (size_t)nt * 8192 + q2 * 256 + n31 * 8;
        bf16x8 xf[16];
        #pragma unroll
        for (int ks = 0; ks < 16; ks++) xf[ks] = *(const bf16x8*)(xg + ks * 512);

        f32x16 acc;
        #pragma unroll
        for (int i = 0; i < 16; i++) acc[i] = 0.f;
        if (ot < 4) {
            #pragma unroll
            for (int ks = 0; ks < 16; ks++)
                acc = __builtin_amdgcn_mfma_f32_32x32x16_bf16(wf[ks], xf[ks], acc, 0, 0, 0);
        } else {
            #pragma unroll
            for (int ks = 0; ks < 16; ks++)
                acc = __builtin_amdgcn_mfma_f32_32x32x16_bf16(xf[ks], wf[ks], acc, 0, 0, 0);
        }

        if (ot < 4) {
            int ocb = (ot < 2) ? B0 : (B0 - 256);
            __bf16* dst = (ot < 2) ? q : k;
            bool isq = (ot < 2);
            #pragma unroll
            for (int gI = 0; gI < 4; gI++) {
                bf16x4 pk;
                #pragma unroll
                for (int j = 0; j < 4; j++) {
                    float y = acc[gI * 4 + j] + bv[gI * 4 + j];
                    if (isq) y *= SCALE;
                    pk[j] = (__bf16)y;
                }
                size_t idx = ((((size_t)(b * 128 + nt) * 16 + ((ocb >> 4) + (gI >> 1))) * 2
                               + (gI & 1)) * 32 + n31) * 8 + 4 * q2;
                *(bf16x4*)(dst + idx) = pk;
            }
        } else {
            int ocb = B0 - 512;
            #pragma unroll
            for (int gI = 0; gI < 4; gI++) {
                bf16x4 pk;
                #pragma unroll
                for (int j = 0; j < 4; j++)
                    pk[j] = (__bf16)(acc[gI * 4 + j] + bvv);
                size_t idx = (((((size_t)(b * 128 + nt) * 2 + (gI >> 1)) * 2 + (gI & 1)) * 8
                               + (ocb >> 5)) * 32 + n31) * 8 + 4 * q2;
                *(bf16x4*)(v + idx) = pk;
            }
        }
    }
}

// ---------------------------------------------------------------------------
// Kernel 3 (R7 = R6 with l moved OFF LDS): producer/consumer attention,
// LDS exactly 81920 B (2x32K K dbuf + 2x8K P) -> 2 blocks/CU restored.
// l exchange via per-block global scratch ltmp[bid][kt][64]: producers
// store row sums before the tail barrier (vmcnt drain at the barrier
// commits them); consumers read both kt slots after it (L2-hit, hidden
// under the tail MFMA), normalize, and store bf16 split-partials.
// Consumer wave 0 writes the summed lpart plane for proj.
// ---------------------------------------------------------------------------
__device__ __forceinline__ void stage16(const __bf16* g, __bf16* l) {
    __builtin_amdgcn_global_load_lds(
        (const __attribute__((address_space(1))) unsigned int*)g,
        (__attribute__((address_space(3))) unsigned int*)l, 16, 0, 0);
}

__global__ __launch_bounds__(512, 4) void attn_kernel(const __bf16* __restrict__ q,
                                                      const __bf16* __restrict__ k,
                                                      const __bf16* __restrict__ v,
                                                      __bf16* __restrict__ aob,
                                                      float* __restrict__ lpart,
                                                      float* __restrict__ ltmp) {
    __shared__ __align__(16) __bf16 k_lds[2][16384];   // 2 x 32 KB double buffer
    __shared__ __align__(16) __bf16 p_lds[2][64 * 64]; // 2 x 8 KB, XOR-swizzled

    int bid   = blockIdx.x;
    int xcd   = bid & 7;
    int b     = xcd >> 1;
    int split = xcd & 1;
    int qt    = bid >> 3;                    // 0..63, 64-row q tile
    int n0    = qt * 64;

    int tid = threadIdx.x;
    int wid = tid >> 6, lane = tid & 63;
    int n31 = lane & 31, q2 = lane >> 5;

    const size_t BSTR = (size_t)N_ * C_;
    const size_t PLANE = (size_t)B_ * C_ * N_;   // elements per split plane
    float* lt = ltmp + (size_t)bid * 128;        // [kt][64] per-block scratch
    // K chunk ch occupies contiguous shorts [ch*16384, +16384) of this
    // block's key range: linear global->LDS copy.
    const __bf16* kgbase = k + (size_t)(b * 128 + split * 64) * 8192
                           + wid * 2048 + lane * 8;

    // prologue: stage chunk 0 into buf 0 (each wave: 4 x 1 KB segments)
    {
        __bf16* l = (__bf16*)k_lds[0] + wid * 2048;
        #pragma unroll
        for (int i = 0; i < 4; i++)
            stage16(kgbase + i * 512, l + i * 512);
    }

    if (wid < 4) {
        // ================= PRODUCER =================
        int kt = wid & 1;                    // 32-key slice within chunk
        int rt = wid >> 1;                   // 32-row tile within 64 rows
        const __bf16* qg = q + (size_t)(b * 128 + qt * 2 + rt) * 8192
                           + q2 * 256 + n31 * 8;
        bf16x8 qf[16];
        #pragma unroll
        for (int ks = 0; ks < 16; ks++) qf[ks] = *(const bf16x8*)(qg + ks * 512);

        float l_acc = 0.f;
        int prow = rt * 32 + n31;
        int swz  = (prow & 7) << 4;
        int klo  = kt * 8192 + q2 * 256 + n31 * 8;

        for (int ch = 0; ch < NCH; ch++) {
            __syncthreads();                 // K[ch] staged, P[(ch-1)] consumed
            if (ch < NCH - 1) {              // stage K[ch+1] into other buffer
                const __bf16* g = kgbase + (size_t)(ch + 1) * 16384;
                __bf16* l = (__bf16*)k_lds[(ch + 1) & 1] + wid * 2048;
                #pragma unroll
                for (int i = 0; i < 4; i++)
                    stage16(g + i * 512, l + i * 512);
            }
            const __bf16* kl = (const __bf16*)k_lds[ch & 1] + klo;
            f32x16 sa, sb;
            #pragma unroll
            for (int i = 0; i < 16; i++) { sa[i] = 0.f; sb[i] = 0.f; }
            __builtin_amdgcn_s_setprio(1);
            #pragma unroll
            for (int i = 0; i < 8; i++) {    // two independent 8-deep chains
                bf16x8 ka = *(const bf16x8*)(kl + i * 512);
                bf16x8 kb = *(const bf16x8*)(kl + (i + 8) * 512);
                sa = __builtin_amdgcn_mfma_f32_32x32x16_bf16(ka, qf[i], sa, 0, 0, 0);
                sb = __builtin_amdgcn_mfma_f32_32x32x16_bf16(kb, qf[i + 8], sb, 0, 0, 0);
            }
            __builtin_amdgcn_s_setprio(0);
            char* pbuf = (char*)p_lds[ch & 1];
            #pragma unroll
            for (int gI = 0; gI < 4; gI++) {
                bf16x4 pw;
                #pragma unroll
                for (int j = 0; j < 4; j++) {
                    float p = __expf(sa[gI * 4 + j] + sb[gI * 4 + j]);
                    l_acc += p;
                    pw[j] = (__bf16)p;
                }
                int off = prow * 128 + kt * 64 + 16 * gI + 8 * q2;
                *(bf16x4*)(pbuf + (off ^ swz)) = pw;
            }
        }
        // l row sums -> global scratch (committed by the barrier's vmcnt drain)
        l_acc += __shfl_down(l_acc, 32);
        if (lane < 32) lt[kt * 64 + rt * 32 + lane] = l_acc;
        __syncthreads();                     // pairs with consumer tail barrier
    } else {
        // ================= CONSUMER =================
        int cw = wid - 4;                    // owns chans [cw*64, +64)
        const __bf16* vbase = v + (size_t)b * BSTR + (size_t)split * 524288
                              + (size_t)q2 * 2048 + n31 * 8;
        f32x16 o_acc[2][2];                  // [ct][rt]
        #pragma unroll
        for (int ct = 0; ct < 2; ct++)
            #pragma unroll
            for (int rt = 0; rt < 2; rt++)
                #pragma unroll
                for (int i = 0; i < 16; i++) o_acc[ct][rt][i] = 0.f;

        for (int ch = 0; ch < NCH; ch++) {
            __syncthreads();
            if (ch < NCH - 1) {              // stage K[ch+1] share
                const __bf16* g = kgbase + (size_t)(ch + 1) * 16384;
                __bf16* l = (__bf16*)k_lds[(ch + 1) & 1] + wid * 2048;
                #pragma unroll
                for (int i = 0; i < 4; i++)
                    stage16(g + i * 512, l + i * 512);
            }
            if (ch > 0) {
                int cc = ch - 1;
                // V loads issued at phase start; covered by pf reads + MFMAs.
                bf16x8 vf[2][4];
                #pragma unroll
                for (int ct = 0; ct < 2; ct++)
                    #pragma unroll
                    for (int ks4 = 0; ks4 < 4; ks4++) {
                        size_t off = (size_t)(cc * 2 + (ks4 >> 1)) * 8192
                                   + (size_t)(ks4 & 1) * 4096 + (cw * 2 + ct) * 256;
                        vf[ct][ks4] = *(const bf16x8*)(vbase + off);
                    }
                const char* pbuf = (const char*)p_lds[cc & 1];
                __builtin_amdgcn_s_setprio(1);
                #pragma unroll
                for (int rt = 0; rt < 2; rt++) {
                    int prow = rt * 32 + n31;
                    int swz  = (prow & 7) << 4;
                    int pbs  = prow * 128 + q2 * 16;
                    #pragma unroll
                    for (int ks4 = 0; ks4 < 4; ks4++) {
                        bf16x8 pf = *(const bf16x8*)(pbuf + ((pbs + ks4 * 32) ^ swz));
                        o_acc[0][rt] = __builtin_amdgcn_mfma_f32_32x32x16_bf16(
                            vf[0][ks4], pf, o_acc[0][rt], 0, 0, 0);
                        o_acc[1][rt] = __builtin_amdgcn_mfma_f32_32x32x16_bf16(
                            vf[1][ks4], pf, o_acc[1][rt], 0, 0, 0);
                    }
                }
                __builtin_amdgcn_s_setprio(0);
            }
        }
        __syncthreads();                     // pairs with producer tail barrier
        // l for rows n31 and 32+n31 (kt slots summed); L2-hit, hidden by tail.
        float lA = lt[n31] + lt[64 + n31];
        float lB = lt[32 + n31] + lt[64 + 32 + n31];
        {   // tail: consume chunk 31 from p_lds[1]
            int cc = NCH - 1;
            bf16x8 vf[2][4];
            #pragma unroll
            for (int ct = 0; ct < 2; ct++)
                #pragma unroll
                for (int ks4 = 0; ks4 < 4; ks4++) {
                    size_t off = (size_t)(cc * 2 + (ks4 >> 1)) * 8192
                               + (size_t)(ks4 & 1) * 4096 + (cw * 2 + ct) * 256;
                    vf[ct][ks4] = *(const bf16x8*)(vbase + off);
                }
            const char* pbuf = (const char*)p_lds[1];
            __builtin_amdgcn_s_setprio(1);
            #pragma unroll
            for (int rt = 0; rt < 2; rt++) {
                int prow = rt * 32 + n31;
                int swz  = (prow & 7) << 4;
                int pbs  = prow * 128 + q2 * 16;
                #pragma unroll
                for (int ks4 = 0; ks4 < 4; ks4++) {
                    bf16x8 pf = *(const bf16x8*)(pbuf + ((pbs + ks4 * 32) ^ swz));
                    o_acc[0][rt] = __builtin_amdgcn_mfma_f32_32x32x16_bf16(
                        vf[0][ks4], pf, o_acc[0][rt], 0, 0, 0);
                    o_acc[1][rt] = __builtin_amdgcn_mfma_f32_32x32x16_bf16(
                        vf[1][ks4], pf, o_acc[1][rt], 0, 0, 0);
                }
            }
            __builtin_amdgcn_s_setprio(0);
        }
        // lpart plane for proj (one consumer wave).
        if (wid == 4 && lane < 32) {
            float* lp = lpart + ((size_t)split * B_ + b) * N_ + n0;
            lp[n31]      = lA;
            lp[32 + n31] = lB;
        }
        // Normalize by split-local l, store bf16 partials (plane per split).
        // Layout: [b][qt][cw][ct][rt][g][q2][n31*4] — coalesced.
        float inv0 = 1.0f / lA;
        float inv1 = 1.0f / lB;
        __bf16* aop = aob + (size_t)split * PLANE;
        #pragma unroll
        for (int ct = 0; ct < 2; ct++)
            #pragma unroll
            for (int rt = 0; rt < 2; rt++) {
                float inv = rt ? inv1 : inv0;
                #pragma unroll
                for (int g = 0; g < 4; g++) {
                    bf16x4 st;
                    #pragma unroll
                    for (int j = 0; j < 4; j++)
                        st[j] = (__bf16)(o_acc[ct][rt][g * 4 + j] * inv);
                    size_t idx = ((((((size_t)(b * 64 + qt) * 4 + cw) * 2 + ct) * 2 + rt)
                                   * 4 + g) * 2 + q2) * 128 + n31 * 4;
                    *(bf16x4*)(aop + idx) = st;
                }
            }
    }
}

// ---------------------------------------------------------------------------
// Kernel 4: out projection. Blends 2 split-normalized bf16 planes with
// weights l_s/(l0+l1), then bf16 MFMA + bias + residual. (unchanged)
// ---------------------------------------------------------------------------
__global__ __launch_bounds__(256) void proj_kernel(const __bf16* __restrict__ aob,
                                                   const float* __restrict__ lpart,
                                                   const float* __restrict__ W2,
                                                   const float* __restrict__ bias,
                                                   const float* __restrict__ x,
                                                   float* __restrict__ out) {
    int b = blockIdx.z, ot = blockIdx.y, nc = blockIdx.x;
    int tid = threadIdx.x, wv = tid >> 6, lane = tid & 63;
    int n31 = lane & 31, q2 = lane >> 5;
    int B0 = ot * 128 + wv * 32;
    const size_t BN = (size_t)B_ * N_;
    const size_t PLANE = (size_t)B_ * C_ * N_;

    bf16x8 wf[16];
    const float* wp = W2 + (size_t)(B0 + n31) * C_;
    #pragma unroll
    for (int ks = 0; ks < 16; ks++) {
        float4 t0 = *(const float4*)(wp + ks * 16 + q2 * 8);
        float4 t1 = *(const float4*)(wp + ks * 16 + q2 * 8 + 4);
        bf16x8 f;
        f[0] = (__bf16)t0.x; f[1] = (__bf16)t0.y; f[2] = (__bf16)t0.z; f[3] = (__bf16)t0.w;
        f[4] = (__bf16)t1.x; f[5] = (__bf16)t1.y; f[6] = (__bf16)t1.z; f[7] = (__bf16)t1.w;
        wf[ks] = f;
    }
    float bv[16];
    #pragma unroll
    for (int r = 0; r < 16; r++) bv[r] = bias[B0 + (r & 3) + 8 * (r >> 2) + 4 * q2];

    for (int t = 0; t < 4; t++) {
        int nt = nc * 4 + t;                  // 32-row tile, 0..127
        int qt = nt >> 1, rtile = nt & 1;
        int n = nt * 32 + n31;
        size_t ln = (size_t)b * N_ + n;
        float l0v = lpart[ln];
        float l1v = lpart[BN + ln];
        float invt = 1.0f / (l0v + l1v);
        float w0 = l0v * invt, w1 = l1v * invt;

        bf16x8 xf[16];
        #pragma unroll
        for (int ks = 0; ks < 16; ks++) {
            int oct = ks * 2 + q2;            // chan octet 0..31
            int cw = oct >> 3, ct = (oct >> 2) & 1, ga = oct & 3;
            size_t base = ((((((size_t)(b * 64 + qt) * 4 + cw) * 2 + ct) * 2 + rtile)
                            * 4 + ga) * 2) * 128 + n31 * 4;
            bf16x4 a0 = *(const bf16x4*)(aob + base);
            bf16x4 b0 = *(const bf16x4*)(aob + base + 128);
            bf16x4 a1 = *(const bf16x4*)(aob + PLANE + base);
            bf16x4 b1 = *(const bf16x4*)(aob + PLANE + base + 128);
            bf16x8 f;
            #pragma unroll
            for (int j = 0; j < 4; j++) {
                f[j]     = (__bf16)(w0 * (float)a0[j] + w1 * (float)a1[j]);
                f[4 + j] = (__bf16)(w0 * (float)b0[j] + w1 * (float)b1[j]);
            }
            xf[ks] = f;
        }

        f32x16 acc;
        #pragma unroll
        for (int i = 0; i < 16; i++) acc[i] = 0.f;
        #pragma unroll
        for (int ks = 0; ks < 16; ks++)
            acc = __builtin_amdgcn_mfma_f32_32x32x16_bf16(wf[ks], xf[ks], acc, 0, 0, 0);

        #pragma unroll
        for (int r = 0; r < 16; r++) {
            int o = B0 + (r & 3) + 8 * (r >> 2) + 4 * q2;
            size_t idx = ((size_t)(b * C_ + o)) * N_ + nt * 32 + n31;
            out[idx] = acc[r] + bv[r] + x[idx];
        }
    }
}

// ---------------------------------------------------------------------------
extern "C" void kernel_launch(void* const* d_in, const int* in_sizes, int n_in,
                              void* d_out, int out_size, void* d_ws, size_t ws_size,
                              hipStream_t stream) {
    const float* x     = (const float*)d_in[0];
    const float* gn_w  = (const float*)d_in[1];
    const float* gn_b  = (const float*)d_in[2];
    const float* qkv_w = (const float*)d_in[3];
    const float* qkv_b = (const float*)d_in[4];
    const float* out_w = (const float*)d_in[5];
    const float* out_b = (const float*)d_in[6];
    float* out = (float*)d_out;

    const size_t SZ = (size_t)B_ * C_ * N_;       // 4,194,304 elements
    char* base = (char*)d_ws;
    __bf16* aob = (__bf16*)base;                  // 2 bf16 planes = 16.8 MB
    __bf16* xnb = (__bf16*)base;                  // aliases aob (dead by attn)
    __bf16* qb  = (__bf16*)(base + 2 * SZ * 4);   // 8.39 MB each
    __bf16* kb  = qb + SZ;
    __bf16* vb  = kb + SZ;
    float*  lpart = (float*)(base + 2 * SZ * 4 + 3 * SZ * 2);  // [2][B][N] fp32
    float*  part  = lpart + 2 * (size_t)B_ * N_;  // [512][2] GN partials
    float*  ltmp  = part + 1024;                  // [512][128] l scratch, 256 KB

    gn_stats_kernel<<<dim3(512), 256, 0, stream>>>(x, part);
    gn_apply_kernel<<<dim3(2048), 256, 0, stream>>>(x, gn_w, gn_b, part, xnb);
    qkv_kernel<<<dim3(32, 6, B_), 256, 0, stream>>>(xnb, qkv_w, qkv_b, qb, kb, vb);
    attn_kernel<<<dim3(512), 512, 0, stream>>>(qb, kb, vb, aob, lpart, ltmp);
    proj_kernel<<<dim3(32, 2, B_), 256, 0, stream>>>(aob, lpart, out_w, out_b, x, out);
}

// Round 8
// 209.167 us; speedup vs baseline: 4.6248x; 1.0024x over previous
//
#include <hip/hip_runtime.h>
#include <math.h>

#define B_   4
#define C_   256
#define G_   32
#define CPG  8                 // channels per group
#define N_   4096              // H*W
#define NPG  (CPG * N_)        // 32768 elements per group
#define EPS  1e-5f
#define SCALE 0.0625f          // C^-0.5 = 1/16
#define NCH  32                // key chunks of 64 per (split) half

typedef __attribute__((ext_vector_type(8)))  __bf16 bf16x8;
typedef __attribute__((ext_vector_type(4)))  __bf16 bf16x4;
typedef __attribute__((ext_vector_type(16))) float  f32x16;

// ---------------------------------------------------------------------------
// Kernel 1a: GroupNorm partial sums (unchanged; x reads are cold HBM).
// ---------------------------------------------------------------------------
__global__ __launch_bounds__(256) void gn_stats_kernel(const float* __restrict__ x,
                                                       float* __restrict__ part) {
    int bid = blockIdx.x;
    int bg = bid >> 2, seg = bid & 3;
    const float4* xp4 = (const float4*)(x + (size_t)bg * NPG) + seg * 2048;
    int tid = threadIdx.x;

    float s = 0.f, ss = 0.f;
    for (int i = tid; i < 2048; i += 256) {
        float4 t = xp4[i];
        s  += t.x + t.y + t.z + t.w;
        ss += t.x * t.x + t.y * t.y + t.z * t.z + t.w * t.w;
    }
    #pragma unroll
    for (int off = 32; off; off >>= 1) {
        s  += __shfl_xor(s, off, 64);
        ss += __shfl_xor(ss, off, 64);
    }
    __shared__ float rs[2][4];
    int wave = tid >> 6, lane = tid & 63;
    if (lane == 0) { rs[0][wave] = s; rs[1][wave] = ss; }
    __syncthreads();
    if (tid == 0) {
        part[bid * 2]     = rs[0][0] + rs[0][1] + rs[0][2] + rs[0][3];
        part[bid * 2 + 1] = rs[1][0] + rs[1][1] + rs[1][2] + rs[1][3];
    }
}

// ---------------------------------------------------------------------------
// Kernel 1b: GroupNorm apply -> bf16 frag-interleaved.
// R8: b pinned to XCD pair (b = (bid&7)>>1) so xnb writes stay dirty in the
// pair's L2 for qkv to hit. Work decode is bijective; body unchanged.
// ---------------------------------------------------------------------------
__global__ __launch_bounds__(256) void gn_apply_kernel(const float* __restrict__ x,
                                                       const float* __restrict__ w,
                                                       const float* __restrict__ bia,
                                                       const float* __restrict__ part,
                                                       __bf16* __restrict__ xnb) {
    int bid = blockIdx.x;
    int b   = (bid & 7) >> 1;
    int u   = ((bid >> 3) << 1) | (bid & 1);   // 0..511
    int g   = u >> 4;
    int seg = u & 15;
    int bg  = b * 32 + g;
    float s  = part[(bg * 4 + 0) * 2] + part[(bg * 4 + 1) * 2]
             + part[(bg * 4 + 2) * 2] + part[(bg * 4 + 3) * 2];
    float ss = part[(bg * 4 + 0) * 2 + 1] + part[(bg * 4 + 1) * 2 + 1]
             + part[(bg * 4 + 2) * 2 + 1] + part[(bg * 4 + 3) * 2 + 1];
    float mean = s / (float)NPG;
    float var  = ss / (float)NPG - mean * mean;
    float rstd = rsqrtf(var + EPS);

    const float* xp = x + (size_t)bg * NPG;
    int n = seg * 256 + threadIdx.x;

    bf16x8 pk;
    #pragma unroll
    for (int cc = 0; cc < 8; cc++) {
        float sc = rstd * w[g * CPG + cc];
        float sh = bia[g * CPG + cc] - mean * sc;
        pk[cc] = (__bf16)(xp[(size_t)cc * N_ + n] * sc + sh);
    }
    size_t idx = ((((size_t)(b * 128 + (n >> 5)) * 16 + (g >> 1)) * 2 + (g & 1))
                  * 32 + (n & 31)) * 8;
    *(bf16x8*)(xnb + idx) = pk;
}

// ---------------------------------------------------------------------------
// Kernel 2: QKV projection, bf16 MFMA.
// R8: 1D grid 768, b pinned to XCD pair -> the 6x ot re-reads of xnb hit
// the pair's L2 (2.1 MB/b) instead of L3/HBM; q/k/v writes stay resident
// for attn (same pair). Body unchanged.
// ---------------------------------------------------------------------------
__global__ __launch_bounds__(256) void qkv_kernel(const __bf16* __restrict__ xnb,
                                                  const float* __restrict__ W,
                                                  const float* __restrict__ bias,
                                                  __bf16* __restrict__ q,
                                                  __bf16* __restrict__ k,
                                                  __bf16* __restrict__ v) {
    int bid = blockIdx.x;
    int b   = (bid & 7) >> 1;
    int t2  = ((bid >> 3) << 1) | (bid & 1);   // 0..191
    int ot  = t2 >> 5;
    int nc  = t2 & 31;
    int tid = threadIdx.x, wv = tid >> 6, lane = tid & 63;
    int n31 = lane & 31, q2 = lane >> 5;
    int B0 = ot * 128 + wv * 32;

    bf16x8 wf[16];
    const float* wp = W + (size_t)(B0 + n31) * C_;
    #pragma unroll
    for (int ks = 0; ks < 16; ks++) {
        float4 t0 = *(const float4*)(wp + ks * 16 + q2 * 8);
        float4 t1 = *(const float4*)(wp + ks * 16 + q2 * 8 + 4);
        bf16x8 f;
        f[0] = (__bf16)t0.x; f[1] = (__bf16)t0.y; f[2] = (__bf16)t0.z; f[3] = (__bf16)t0.w;
        f[4] = (__bf16)t1.x; f[5] = (__bf16)t1.y; f[6] = (__bf16)t1.z; f[7] = (__bf16)t1.w;
        wf[ks] = f;
    }

    float bv[16], bvv = 0.f;
    if (ot < 4) {
        #pragma unroll
        for (int gI = 0; gI < 4; gI++)
            #pragma unroll
            for (int j = 0; j < 4; j++)
                bv[gI * 4 + j] = bias[B0 + gI * 8 + 4 * q2 + j];
    } else {
        bvv = bias[B0 + n31];
    }

    const __bf16* xb = xnb + (size_t)b * 128 * 8192;

    for (int t = 0; t < 4; t++) {
        int nt = nc * 4 + t;
        const __bf16* xg = xb + (size_t)nt * 8192 + q2 * 256 + n31 * 8;
        bf16x8 xf[16];
        #pragma unroll
        for (int ks = 0; ks < 16; ks++) xf[ks] = *(const bf16x8*)(xg + ks * 512);

        f32x16 acc;
        #pragma unroll
        for (int i = 0; i < 16; i++) acc[i] = 0.f;
        if (ot < 4) {
            #pragma unroll
            for (int ks = 0; ks < 16; ks++)
                acc = __builtin_amdgcn_mfma_f32_32x32x16_bf16(wf[ks], xf[ks], acc, 0, 0, 0);
        } else {
            #pragma unroll
            for (int ks = 0; ks < 16; ks++)
                acc = __builtin_amdgcn_mfma_f32_32x32x16_bf16(xf[ks], wf[ks], acc, 0, 0, 0);
        }

        if (ot < 4) {
            int ocb = (ot < 2) ? B0 : (B0 - 256);
            __bf16* dst = (ot < 2) ? q : k;
            bool isq = (ot < 2);
            #pragma unroll
            for (int gI = 0; gI < 4; gI++) {
                bf16x4 pk;
                #pragma unroll
                for (int j = 0; j < 4; j++) {
                    float y = acc[gI * 4 + j] + bv[gI * 4 + j];
                    if (isq) y *= SCALE;
                    pk[j] = (__bf16)y;
                }
                size_t idx = ((((size_t)(b * 128 + nt) * 16 + ((ocb >> 4) + (gI >> 1))) * 2
                               + (gI & 1)) * 32 + n31) * 8 + 4 * q2;
                *(bf16x4*)(dst + idx) = pk;
            }
        } else {
            int ocb = B0 - 512;
            #pragma unroll
            for (int gI = 0; gI < 4; gI++) {
                bf16x4 pk;
                #pragma unroll
                for (int j = 0; j < 4; j++)
                    pk[j] = (__bf16)(acc[gI * 4 + j] + bvv);
                size_t idx = (((((size_t)(b * 128 + nt) * 2 + (gI >> 1)) * 2 + (gI & 1)) * 8
                               + (ocb >> 5)) * 32 + n31) * 8 + 4 * q2;
                *(bf16x4*)(v + idx) = pk;
            }
        }
    }
}

// ---------------------------------------------------------------------------
// Kernel 3 (unchanged from R7): producer/consumer attention, LDS 81920,
// l via global scratch. b already pinned to XCD pair (xcd = bid&7,
// b = xcd>>1, split = xcd&1) — q/k/v should now be L2-resident from qkv.
// ---------------------------------------------------------------------------
__device__ __forceinline__ void stage16(const __bf16* g, __bf16* l) {
    __builtin_amdgcn_global_load_lds(
        (const __attribute__((address_space(1))) unsigned int*)g,
        (__attribute__((address_space(3))) unsigned int*)l, 16, 0, 0);
}

__global__ __launch_bounds__(512, 4) void attn_kernel(const __bf16* __restrict__ q,
                                                      const __bf16* __restrict__ k,
                                                      const __bf16* __restrict__ v,
                                                      __bf16* __restrict__ aob,
                                                      float* __restrict__ lpart,
                                                      float* __restrict__ ltmp) {
    __shared__ __align__(16) __bf16 k_lds[2][16384];   // 2 x 32 KB double buffer
    __shared__ __align__(16) __bf16 p_lds[2][64 * 64]; // 2 x 8 KB, XOR-swizzled

    int bid   = blockIdx.x;
    int xcd   = bid & 7;
    int b     = xcd >> 1;
    int split = xcd & 1;
    int qt    = bid >> 3;                    // 0..63, 64-row q tile
    int n0    = qt * 64;

    int tid = threadIdx.x;
    int wid = tid >> 6, lane = tid & 63;
    int n31 = lane & 31, q2 = lane >> 5;

    const size_t BSTR = (size_t)N_ * C_;
    const size_t PLANE = (size_t)B_ * C_ * N_;   // elements per split plane
    float* lt = ltmp + (size_t)bid * 128;        // [kt][64] per-block scratch
    const __bf16* kgbase = k + (size_t)(b * 128 + split * 64) * 8192
                           + wid * 2048 + lane * 8;

    // prologue: stage chunk 0 into buf 0 (each wave: 4 x 1 KB segments)
    {
        __bf16* l = (__bf16*)k_lds[0] + wid * 2048;
        #pragma unroll
        for (int i = 0; i < 4; i++)
            stage16(kgbase + i * 512, l + i * 512);
    }

    if (wid < 4) {
        // ================= PRODUCER =================
        int kt = wid & 1;                    // 32-key slice within chunk
        int rt = wid >> 1;                   // 32-row tile within 64 rows
        const __bf16* qg = q + (size_t)(b * 128 + qt * 2 + rt) * 8192
                           + q2 * 256 + n31 * 8;
        bf16x8 qf[16];
        #pragma unroll
        for (int ks = 0; ks < 16; ks++) qf[ks] = *(const bf16x8*)(qg + ks * 512);

        float l_acc = 0.f;
        int prow = rt * 32 + n31;
        int swz  = (prow & 7) << 4;
        int klo  = kt * 8192 + q2 * 256 + n31 * 8;

        for (int ch = 0; ch < NCH; ch++) {
            __syncthreads();                 // K[ch] staged, P[(ch-1)] consumed
            if (ch < NCH - 1) {              // stage K[ch+1] into other buffer
                const __bf16* g = kgbase + (size_t)(ch + 1) * 16384;
                __bf16* l = (__bf16*)k_lds[(ch + 1) & 1] + wid * 2048;
                #pragma unroll
                for (int i = 0; i < 4; i++)
                    stage16(g + i * 512, l + i * 512);
            }
            const __bf16* kl = (const __bf16*)k_lds[ch & 1] + klo;
            f32x16 sa, sb;
            #pragma unroll
            for (int i = 0; i < 16; i++) { sa[i] = 0.f; sb[i] = 0.f; }
            __builtin_amdgcn_s_setprio(1);
            #pragma unroll
            for (int i = 0; i < 8; i++) {    // two independent 8-deep chains
                bf16x8 ka = *(const bf16x8*)(kl + i * 512);
                bf16x8 kb = *(const bf16x8*)(kl + (i + 8) * 512);
                sa = __builtin_amdgcn_mfma_f32_32x32x16_bf16(ka, qf[i], sa, 0, 0, 0);
                sb = __builtin_amdgcn_mfma_f32_32x32x16_bf16(kb, qf[i + 8], sb, 0, 0, 0);
            }
            __builtin_amdgcn_s_setprio(0);
            char* pbuf = (char*)p_lds[ch & 1];
            #pragma unroll
            for (int gI = 0; gI < 4; gI++) {
                bf16x4 pw;
                #pragma unroll
                for (int j = 0; j < 4; j++) {
                    float p = __expf(sa[gI * 4 + j] + sb[gI * 4 + j]);
                    l_acc += p;
                    pw[j] = (__bf16)p;
                }
                int off = prow * 128 + kt * 64 + 16 * gI + 8 * q2;
                *(bf16x4*)(pbuf + (off ^ swz)) = pw;
            }
        }
        // l row sums -> global scratch (committed by the barrier's vmcnt drain)
        l_acc += __shfl_down(l_acc, 32);
        if (lane < 32) lt[kt * 64 + rt * 32 + lane] = l_acc;
        __syncthreads();                     // pairs with consumer tail barrier
    } else {
        // ================= CONSUMER =================
        int cw = wid - 4;                    // owns chans [cw*64, +64)
        const __bf16* vbase = v + (size_t)b * BSTR + (size_t)split * 524288
                              + (size_t)q2 * 2048 + n31 * 8;
        f32x16 o_acc[2][2];                  // [ct][rt]
        #pragma unroll
        for (int ct = 0; ct < 2; ct++)
            #pragma unroll
            for (int rt = 0; rt < 2; rt++)
                #pragma unroll
                for (int i = 0; i < 16; i++) o_acc[ct][rt][i] = 0.f;

        for (int ch = 0; ch < NCH; ch++) {
            __syncthreads();
            if (ch < NCH - 1) {              // stage K[ch+1] share
                const __bf16* g = kgbase + (size_t)(ch + 1) * 16384;
                __bf16* l = (__bf16*)k_lds[(ch + 1) & 1] + wid * 2048;
                #pragma unroll
                for (int i = 0; i < 4; i++)
                    stage16(g + i * 512, l + i * 512);
            }
            if (ch > 0) {
                int cc = ch - 1;
                // V loads issued at phase start; covered by pf reads + MFMAs.
                bf16x8 vf[2][4];
                #pragma unroll
                for (int ct = 0; ct < 2; ct++)
                    #pragma unroll
                    for (int ks4 = 0; ks4 < 4; ks4++) {
                        size_t off = (size_t)(cc * 2 + (ks4 >> 1)) * 8192
                                   + (size_t)(ks4 & 1) * 4096 + (cw * 2 + ct) * 256;
                        vf[ct][ks4] = *(const bf16x8*)(vbase + off);
                    }
                const char* pbuf = (const char*)p_lds[cc & 1];
                __builtin_amdgcn_s_setprio(1);
                #pragma unroll
                for (int rt = 0; rt < 2; rt++) {
                    int prow = rt * 32 + n31;
                    int swz  = (prow & 7) << 4;
                    int pbs  = prow * 128 + q2 * 16;
                    #pragma unroll
                    for (int ks4 = 0; ks4 < 4; ks4++) {
                        bf16x8 pf = *(const bf16x8*)(pbuf + ((pbs + ks4 * 32) ^ swz));
                        o_acc[0][rt] = __builtin_amdgcn_mfma_f32_32x32x16_bf16(
                            vf[0][ks4], pf, o_acc[0][rt], 0, 0, 0);
                        o_acc[1][rt] = __builtin_amdgcn_mfma_f32_32x32x16_bf16(
                            vf[1][ks4], pf, o_acc[1][rt], 0, 0, 0);
                    }
                }
                __builtin_amdgcn_s_setprio(0);
            }
        }
        __syncthreads();                     // pairs with producer tail barrier
        // l for rows n31 and 32+n31 (kt slots summed); L2-hit, hidden by tail.
        float lA = lt[n31] + lt[64 + n31];
        float lB = lt[32 + n31] + lt[64 + 32 + n31];
        {   // tail: consume chunk 31 from p_lds[1]
            int cc = NCH - 1;
            bf16x8 vf[2][4];
            #pragma unroll
            for (int ct = 0; ct < 2; ct++)
                #pragma unroll
                for (int ks4 = 0; ks4 < 4; ks4++) {
                    size_t off = (size_t)(cc * 2 + (ks4 >> 1)) * 8192
                               + (size_t)(ks4 & 1) * 4096 + (cw * 2 + ct) * 256;
                    vf[ct][ks4] = *(const bf16x8*)(vbase + off);
                }
            const char* pbuf = (const char*)p_lds[1];
            __builtin_amdgcn_s_setprio(1);
            #pragma unroll
            for (int rt = 0; rt < 2; rt++) {
                int prow = rt * 32 + n31;
                int swz  = (prow & 7) << 4;
                int pbs  = prow * 128 + q2 * 16;
                #pragma unroll
                for (int ks4 = 0; ks4 < 4; ks4++) {
                    bf16x8 pf = *(const bf16x8*)(pbuf + ((pbs + ks4 * 32) ^ swz));
                    o_acc[0][rt] = __builtin_amdgcn_mfma_f32_32x32x16_bf16(
                        vf[0][ks4], pf, o_acc[0][rt], 0, 0, 0);
                    o_acc[1][rt] = __builtin_amdgcn_mfma_f32_32x32x16_bf16(
                        vf[1][ks4], pf, o_acc[1][rt], 0, 0, 0);
                }
            }
            __builtin_amdgcn_s_setprio(0);
        }
        // lpart plane for proj (one consumer wave).
        if (wid == 4 && lane < 32) {
            float* lp = lpart + ((size_t)split * B_ + b) * N_ + n0;
            lp[n31]      = lA;
            lp[32 + n31] = lB;
        }
        // Normalize by split-local l, store bf16 partials (plane per split).
        float inv0 = 1.0f / lA;
        float inv1 = 1.0f / lB;
        __bf16* aop = aob + (size_t)split * PLANE;
        #pragma unroll
        for (int ct = 0; ct < 2; ct++)
            #pragma unroll
            for (int rt = 0; rt < 2; rt++) {
                float inv = rt ? inv1 : inv0;
                #pragma unroll
                for (int g = 0; g < 4; g++) {
                    bf16x4 st;
                    #pragma unroll
                    for (int j = 0; j < 4; j++)
                        st[j] = (__bf16)(o_acc[ct][rt][g * 4 + j] * inv);
                    size_t idx = ((((((size_t)(b * 64 + qt) * 4 + cw) * 2 + ct) * 2 + rt)
                                   * 4 + g) * 2 + q2) * 128 + n31 * 4;
                    *(bf16x4*)(aop + idx) = st;
                }
            }
    }
}

// ---------------------------------------------------------------------------
// Kernel 4: out projection. R8: 1D grid 256 with b pinned to the same XCD
// pair as attn (aob half-local in L2). Body unchanged.
// ---------------------------------------------------------------------------
__global__ __launch_bounds__(256) void proj_kernel(const __bf16* __restrict__ aob,
                                                   const float* __restrict__ lpart,
                                                   const float* __restrict__ W2,
                                                   const float* __restrict__ bias,
                                                   const float* __restrict__ x,
                                                   float* __restrict__ out) {
    int bid = blockIdx.x;
    int b   = (bid & 7) >> 1;
    int u   = ((bid >> 3) << 1) | (bid & 1);   // 0..63
    int ot  = u >> 5;
    int nc  = u & 31;
    int tid = threadIdx.x, wv = tid >> 6, lane = tid & 63;
    int n31 = lane & 31, q2 = lane >> 5;
    int B0 = ot * 128 + wv * 32;
    const size_t BN = (size_t)B_ * N_;
    const size_t PLANE = (size_t)B_ * C_ * N_;

    bf16x8 wf[16];
    const float* wp = W2 + (size_t)(B0 + n31) * C_;
    #pragma unroll
    for (int ks = 0; ks < 16; ks++) {
        float4 t0 = *(const float4*)(wp + ks * 16 + q2 * 8);
        float4 t1 = *(const float4*)(wp + ks * 16 + q2 * 8 + 4);
        bf16x8 f;
        f[0] = (__bf16)t0.x; f[1] = (__bf16)t0.y; f[2] = (__bf16)t0.z; f[3] = (__bf16)t0.w;
        f[4] = (__bf16)t1.x; f[5] = (__bf16)t1.y; f[6] = (__bf16)t1.z; f[7] = (__bf16)t1.w;
        wf[ks] = f;
    }
    float bv[16];
    #pragma unroll
    for (int r = 0; r < 16; r++) bv[r] = bias[B0 + (r & 3) + 8 * (r >> 2) + 4 * q2];

    for (int t = 0; t < 4; t++) {
        int nt = nc * 4 + t;                  // 32-row tile, 0..127
        int qt = nt >> 1, rtile = nt & 1;
        int n = nt * 32 + n31;
        size_t ln = (size_t)b * N_ + n;
        float l0v = lpart[ln];
        float l1v = lpart[BN + ln];
        float invt = 1.0f / (l0v + l1v);
        float w0 = l0v * invt, w1 = l1v * invt;

        bf16x8 xf[16];
        #pragma unroll
        for (int ks = 0; ks < 16; ks++) {
            int oct = ks * 2 + q2;            // chan octet 0..31
            int cw = oct >> 3, ct = (oct >> 2) & 1, ga = oct & 3;
            size_t base = ((((((size_t)(b * 64 + qt) * 4 + cw) * 2 + ct) * 2 + rtile)
                            * 4 + ga) * 2) * 128 + n31 * 4;
            bf16x4 a0 = *(const bf16x4*)(aob + base);
            bf16x4 b0 = *(const bf16x4*)(aob + base + 128);
            bf16x4 a1 = *(const bf16x4*)(aob + PLANE + base);
            bf16x4 b1 = *(const bf16x4*)(aob + PLANE + base + 128);
            bf16x8 f;
            #pragma unroll
            for (int j = 0; j < 4; j++) {
                f[j]     = (__bf16)(w0 * (float)a0[j] + w1 * (float)a1[j]);
                f[4 + j] = (__bf16)(w0 * (float)b0[j] + w1 * (float)b1[j]);
            }
            xf[ks] = f;
        }

        f32x16 acc;
        #pragma unroll
        for (int i = 0; i < 16; i++) acc[i] = 0.f;
        #pragma unroll
        for (int ks = 0; ks < 16; ks++)
            acc = __builtin_amdgcn_mfma_f32_32x32x16_bf16(wf[ks], xf[ks], acc, 0, 0, 0);

        #pragma unroll
        for (int r = 0; r < 16; r++) {
            int o = B0 + (r & 3) + 8 * (r >> 2) + 4 * q2;
            size_t idx = ((size_t)(b * C_ + o)) * N_ + nt * 32 + n31;
            out[idx] = acc[r] + bv[r] + x[idx];
        }
    }
}

// ---------------------------------------------------------------------------
extern "C" void kernel_launch(void* const* d_in, const int* in_sizes, int n_in,
                              void* d_out, int out_size, void* d_ws, size_t ws_size,
                              hipStream_t stream) {
    const float* x     = (const float*)d_in[0];
    const float* gn_w  = (const float*)d_in[1];
    const float* gn_b  = (const float*)d_in[2];
    const float* qkv_w = (const float*)d_in[3];
    const float* qkv_b = (const float*)d_in[4];
    const float* out_w = (const float*)d_in[5];
    const float* out_b = (const float*)d_in[6];
    float* out = (float*)d_out;

    const size_t SZ = (size_t)B_ * C_ * N_;       // 4,194,304 elements
    char* base = (char*)d_ws;
    __bf16* aob = (__bf16*)base;                  // 2 bf16 planes = 16.8 MB
    __bf16* xnb = (__bf16*)base;                  // aliases aob (dead by attn)
    __bf16* qb  = (__bf16*)(base + 2 * SZ * 4);   // 8.39 MB each
    __bf16* kb  = qb + SZ;
    __bf16* vb  = kb + SZ;
    float*  lpart = (float*)(base + 2 * SZ * 4 + 3 * SZ * 2);  // [2][B][N] fp32
    float*  part  = lpart + 2 * (size_t)B_ * N_;  // [512][2] GN partials
    float*  ltmp  = part + 1024;                  // [512][128] l scratch, 256 KB

    gn_stats_kernel<<<dim3(512), 256, 0, stream>>>(x, part);
    gn_apply_kernel<<<dim3(2048), 256, 0, stream>>>(x, gn_w, gn_b, part, xnb);
    qkv_kernel<<<dim3(768), 256, 0, stream>>>(xnb, qkv_w, qkv_b, qb, kb, vb);
    attn_kernel<<<dim3(512), 512, 0, stream>>>(qb, kb, vb, aob, lpart, ltmp);
    proj_kernel<<<dim3(256), 256, 0, stream>>>(aob, lpart, out_w, out_b, x, out);
}

// Round 9
// 204.964 us; speedup vs baseline: 4.7197x; 1.0205x over previous
//
#include <hip/hip_runtime.h>
#include <math.h>

#define B_   4
#define C_   256
#define G_   32
#define CPG  8                 // channels per group
#define N_   4096              // H*W
#define NPG  (CPG * N_)        // 32768 elements per group
#define EPS  1e-5f
#define SCALE 0.0625f          // C^-0.5 = 1/16
#define NCH  32                // key chunks of 64 per (split) half

typedef __attribute__((ext_vector_type(8)))  __bf16 bf16x8;
typedef __attribute__((ext_vector_type(4)))  __bf16 bf16x4;
typedef __attribute__((ext_vector_type(16))) float  f32x16;

__device__ __forceinline__ void stage16(const __bf16* g, __bf16* l) {
    __builtin_amdgcn_global_load_lds(
        (const __attribute__((address_space(1))) unsigned int*)g,
        (__attribute__((address_space(3))) unsigned int*)l, 16, 0, 0);
}

// ---------------------------------------------------------------------------
// Kernel 1a: GroupNorm partial sums (unchanged).
// ---------------------------------------------------------------------------
__global__ __launch_bounds__(256) void gn_stats_kernel(const float* __restrict__ x,
                                                       float* __restrict__ part) {
    int bid = blockIdx.x;
    int bg = bid >> 2, seg = bid & 3;
    const float4* xp4 = (const float4*)(x + (size_t)bg * NPG) + seg * 2048;
    int tid = threadIdx.x;

    float s = 0.f, ss = 0.f;
    for (int i = tid; i < 2048; i += 256) {
        float4 t = xp4[i];
        s  += t.x + t.y + t.z + t.w;
        ss += t.x * t.x + t.y * t.y + t.z * t.z + t.w * t.w;
    }
    #pragma unroll
    for (int off = 32; off; off >>= 1) {
        s  += __shfl_xor(s, off, 64);
        ss += __shfl_xor(ss, off, 64);
    }
    __shared__ float rs[2][4];
    int wave = tid >> 6, lane = tid & 63;
    if (lane == 0) { rs[0][wave] = s; rs[1][wave] = ss; }
    __syncthreads();
    if (tid == 0) {
        part[bid * 2]     = rs[0][0] + rs[0][1] + rs[0][2] + rs[0][3];
        part[bid * 2 + 1] = rs[1][0] + rs[1][1] + rs[1][2] + rs[1][3];
    }
}

// ---------------------------------------------------------------------------
// Kernel 1b (R9): GroupNorm apply, float4-vectorized. Each thread handles
// 4 consecutive n for all 8 cc: 8 x float4 loads (128 B/thread) + 4
// contiguous bf16x8 stores (64 B/thread). Grid 512.
// ---------------------------------------------------------------------------
__global__ __launch_bounds__(256) void gn_apply_kernel(const float* __restrict__ x,
                                                       const float* __restrict__ w,
                                                       const float* __restrict__ bia,
                                                       const float* __restrict__ part,
                                                       __bf16* __restrict__ xnb) {
    int bid = blockIdx.x;                      // 0..511
    int b   = (bid & 7) >> 1;
    int u   = ((bid >> 3) << 1) | (bid & 1);   // 0..127
    int g   = u >> 2;
    int seg = u & 3;
    int bg  = b * 32 + g;
    float s  = part[(bg * 4 + 0) * 2] + part[(bg * 4 + 1) * 2]
             + part[(bg * 4 + 2) * 2] + part[(bg * 4 + 3) * 2];
    float ss = part[(bg * 4 + 0) * 2 + 1] + part[(bg * 4 + 1) * 2 + 1]
             + part[(bg * 4 + 2) * 2 + 1] + part[(bg * 4 + 3) * 2 + 1];
    float mean = s / (float)NPG;
    float var  = ss / (float)NPG - mean * mean;
    float rstd = rsqrtf(var + EPS);

    const float* xp = x + (size_t)bg * NPG;
    int n0 = seg * 1024 + threadIdx.x * 4;

    float4 t[8];
    #pragma unroll
    for (int cc = 0; cc < 8; cc++)
        t[cc] = *(const float4*)(xp + (size_t)cc * N_ + n0);

    float sc[8], sh[8];
    #pragma unroll
    for (int cc = 0; cc < 8; cc++) {
        sc[cc] = rstd * w[g * CPG + cc];
        sh[cc] = bia[g * CPG + cc] - mean * sc[cc];
    }

    size_t base = ((((size_t)(b * 128 + (n0 >> 5)) * 16 + (g >> 1)) * 2 + (g & 1))
                   * 32 + (n0 & 31)) * 8;
    #pragma unroll
    for (int j = 0; j < 4; j++) {
        bf16x8 pk;
        #pragma unroll
        for (int cc = 0; cc < 8; cc++) {
            float tv = ((const float*)&t[cc])[j];
            pk[cc] = (__bf16)(tv * sc[cc] + sh[cc]);
        }
        *(bf16x8*)(xnb + base + j * 8) = pk;
    }
}

// ---------------------------------------------------------------------------
// Kernel 2 (R9): QKV projection. The 4 waves of a block all consume the
// SAME 16 KB xnb tile -> stage it once via global_load_lds double-buffer
// (R3's proven attn pattern): kills the 4x wave-dup on the L1/L2 return
// path and moves xf off the MFMA critical path (ds_read_b128,
// conflict-free). LDS 32 KB. Grid 768, body/epilogue otherwise unchanged.
// ---------------------------------------------------------------------------
__global__ __launch_bounds__(256) void qkv_kernel(const __bf16* __restrict__ xnb,
                                                  const float* __restrict__ W,
                                                  const float* __restrict__ bias,
                                                  __bf16* __restrict__ q,
                                                  __bf16* __restrict__ k,
                                                  __bf16* __restrict__ v) {
    __shared__ __align__(16) __bf16 x_lds[2][8192];   // 2 x 16 KB
    int bid = blockIdx.x;
    int b   = (bid & 7) >> 1;
    int t2  = ((bid >> 3) << 1) | (bid & 1);   // 0..191
    int ot  = t2 >> 5;
    int nc  = t2 & 31;
    int tid = threadIdx.x, wv = tid >> 6, lane = tid & 63;
    int n31 = lane & 31, q2 = lane >> 5;
    int B0 = ot * 128 + wv * 32;

    bf16x8 wf[16];
    const float* wp = W + (size_t)(B0 + n31) * C_;
    #pragma unroll
    for (int ks = 0; ks < 16; ks++) {
        float4 t0 = *(const float4*)(wp + ks * 16 + q2 * 8);
        float4 t1 = *(const float4*)(wp + ks * 16 + q2 * 8 + 4);
        bf16x8 f;
        f[0] = (__bf16)t0.x; f[1] = (__bf16)t0.y; f[2] = (__bf16)t0.z; f[3] = (__bf16)t0.w;
        f[4] = (__bf16)t1.x; f[5] = (__bf16)t1.y; f[6] = (__bf16)t1.z; f[7] = (__bf16)t1.w;
        wf[ks] = f;
    }

    float bv[16], bvv = 0.f;
    if (ot < 4) {
        #pragma unroll
        for (int gI = 0; gI < 4; gI++)
            #pragma unroll
            for (int j = 0; j < 4; j++)
                bv[gI * 4 + j] = bias[B0 + gI * 8 + 4 * q2 + j];
    } else {
        bvv = bias[B0 + n31];
    }

    const __bf16* xb = xnb + (size_t)b * 128 * 8192;
    const __bf16* xgs = xb + (size_t)(nc * 4) * 8192 + wv * 2048 + lane * 8;

    {   // prologue: stage tile 0
        __bf16* l = (__bf16*)x_lds[0] + wv * 2048;
        #pragma unroll
        for (int i = 0; i < 4; i++)
            stage16(xgs + i * 512, l + i * 512);
    }

    for (int t = 0; t < 4; t++) {
        __syncthreads();                      // tile t staged
        if (t < 3) {                          // stage tile t+1
            const __bf16* g_ = xgs + (size_t)(t + 1) * 8192;
            __bf16* l = (__bf16*)x_lds[(t + 1) & 1] + wv * 2048;
            #pragma unroll
            for (int i = 0; i < 4; i++)
                stage16(g_ + i * 512, l + i * 512);
        }
        int nt = nc * 4 + t;
        const __bf16* xl = (const __bf16*)x_lds[t & 1] + q2 * 256 + n31 * 8;
        bf16x8 xf[16];
        #pragma unroll
        for (int ks = 0; ks < 16; ks++) xf[ks] = *(const bf16x8*)(xl + ks * 512);

        f32x16 acc;
        #pragma unroll
        for (int i = 0; i < 16; i++) acc[i] = 0.f;
        if (ot < 4) {
            #pragma unroll
            for (int ks = 0; ks < 16; ks++)
                acc = __builtin_amdgcn_mfma_f32_32x32x16_bf16(wf[ks], xf[ks], acc, 0, 0, 0);
        } else {
            #pragma unroll
            for (int ks = 0; ks < 16; ks++)
                acc = __builtin_amdgcn_mfma_f32_32x32x16_bf16(xf[ks], wf[ks], acc, 0, 0, 0);
        }

        if (ot < 4) {
            int ocb = (ot < 2) ? B0 : (B0 - 256);
            __bf16* dst = (ot < 2) ? q : k;
            bool isq = (ot < 2);
            #pragma unroll
            for (int gI = 0; gI < 4; gI++) {
                bf16x4 pk;
                #pragma unroll
                for (int j = 0; j < 4; j++) {
                    float y = acc[gI * 4 + j] + bv[gI * 4 + j];
                    if (isq) y *= SCALE;
                    pk[j] = (__bf16)y;
                }
                size_t idx = ((((size_t)(b * 128 + nt) * 16 + ((ocb >> 4) + (gI >> 1))) * 2
                               + (gI & 1)) * 32 + n31) * 8 + 4 * q2;
                *(bf16x4*)(dst + idx) = pk;
            }
        } else {
            int ocb = B0 - 512;
            #pragma unroll
            for (int gI = 0; gI < 4; gI++) {
                bf16x4 pk;
                #pragma unroll
                for (int j = 0; j < 4; j++)
                    pk[j] = (__bf16)(acc[gI * 4 + j] + bvv);
                size_t idx = (((((size_t)(b * 128 + nt) * 2 + (gI >> 1)) * 2 + (gI & 1)) * 8
                               + (ocb >> 5)) * 32 + n31) * 8 + 4 * q2;
                *(bf16x4*)(v + idx) = pk;
            }
        }
    }
}

// ---------------------------------------------------------------------------
// Kernel 3 (unchanged from R7/R8): producer/consumer attention.
// ---------------------------------------------------------------------------
__global__ __launch_bounds__(512, 4) void attn_kernel(const __bf16* __restrict__ q,
                                                      const __bf16* __restrict__ k,
                                                      const __bf16* __restrict__ v,
                                                      __bf16* __restrict__ aob,
                                                      float* __restrict__ lpart,
                                                      float* __restrict__ ltmp) {
    __shared__ __align__(16) __bf16 k_lds[2][16384];   // 2 x 32 KB double buffer
    __shared__ __align__(16) __bf16 p_lds[2][64 * 64]; // 2 x 8 KB, XOR-swizzled

    int bid   = blockIdx.x;
    int xcd   = bid & 7;
    int b     = xcd >> 1;
    int split = xcd & 1;
    int qt    = bid >> 3;                    // 0..63, 64-row q tile
    int n0    = qt * 64;

    int tid = threadIdx.x;
    int wid = tid >> 6, lane = tid & 63;
    int n31 = lane & 31, q2 = lane >> 5;

    const size_t BSTR = (size_t)N_ * C_;
    const size_t PLANE = (size_t)B_ * C_ * N_;   // elements per split plane
    float* lt = ltmp + (size_t)bid * 128;        // [kt][64] per-block scratch
    const __bf16* kgbase = k + (size_t)(b * 128 + split * 64) * 8192
                           + wid * 2048 + lane * 8;

    // prologue: stage chunk 0 into buf 0 (each wave: 4 x 1 KB segments)
    {
        __bf16* l = (__bf16*)k_lds[0] + wid * 2048;
        #pragma unroll
        for (int i = 0; i < 4; i++)
            stage16(kgbase + i * 512, l + i * 512);
    }

    if (wid < 4) {
        // ================= PRODUCER =================
        int kt = wid & 1;                    // 32-key slice within chunk
        int rt = wid >> 1;                   // 32-row tile within 64 rows
        const __bf16* qg = q + (size_t)(b * 128 + qt * 2 + rt) * 8192
                           + q2 * 256 + n31 * 8;
        bf16x8 qf[16];
        #pragma unroll
        for (int ks = 0; ks < 16; ks++) qf[ks] = *(const bf16x8*)(qg + ks * 512);

        float l_acc = 0.f;
        int prow = rt * 32 + n31;
        int swz  = (prow & 7) << 4;
        int klo  = kt * 8192 + q2 * 256 + n31 * 8;

        for (int ch = 0; ch < NCH; ch++) {
            __syncthreads();                 // K[ch] staged, P[(ch-1)] consumed
            if (ch < NCH - 1) {              // stage K[ch+1] into other buffer
                const __bf16* g = kgbase + (size_t)(ch + 1) * 16384;
                __bf16* l = (__bf16*)k_lds[(ch + 1) & 1] + wid * 2048;
                #pragma unroll
                for (int i = 0; i < 4; i++)
                    stage16(g + i * 512, l + i * 512);
            }
            const __bf16* kl = (const __bf16*)k_lds[ch & 1] + klo;
            f32x16 sa, sb;
            #pragma unroll
            for (int i = 0; i < 16; i++) { sa[i] = 0.f; sb[i] = 0.f; }
            __builtin_amdgcn_s_setprio(1);
            #pragma unroll
            for (int i = 0; i < 8; i++) {    // two independent 8-deep chains
                bf16x8 ka = *(const bf16x8*)(kl + i * 512);
                bf16x8 kb = *(const bf16x8*)(kl + (i + 8) * 512);
                sa = __builtin_amdgcn_mfma_f32_32x32x16_bf16(ka, qf[i], sa, 0, 0, 0);
                sb = __builtin_amdgcn_mfma_f32_32x32x16_bf16(kb, qf[i + 8], sb, 0, 0, 0);
            }
            __builtin_amdgcn_s_setprio(0);
            char* pbuf = (char*)p_lds[ch & 1];
            #pragma unroll
            for (int gI = 0; gI < 4; gI++) {
                bf16x4 pw;
                #pragma unroll
                for (int j = 0; j < 4; j++) {
                    float p = __expf(sa[gI * 4 + j] + sb[gI * 4 + j]);
                    l_acc += p;
                    pw[j] = (__bf16)p;
                }
                int off = prow * 128 + kt * 64 + 16 * gI + 8 * q2;
                *(bf16x4*)(pbuf + (off ^ swz)) = pw;
            }
        }
        // l row sums -> global scratch (committed by the barrier's vmcnt drain)
        l_acc += __shfl_down(l_acc, 32);
        if (lane < 32) lt[kt * 64 + rt * 32 + lane] = l_acc;
        __syncthreads();                     // pairs with consumer tail barrier
    } else {
        // ================= CONSUMER =================
        int cw = wid - 4;                    // owns chans [cw*64, +64)
        const __bf16* vbase = v + (size_t)b * BSTR + (size_t)split * 524288
                              + (size_t)q2 * 2048 + n31 * 8;
        f32x16 o_acc[2][2];                  // [ct][rt]
        #pragma unroll
        for (int ct = 0; ct < 2; ct++)
            #pragma unroll
            for (int rt = 0; rt < 2; rt++)
                #pragma unroll
                for (int i = 0; i < 16; i++) o_acc[ct][rt][i] = 0.f;

        for (int ch = 0; ch < NCH; ch++) {
            __syncthreads();
            if (ch < NCH - 1) {              // stage K[ch+1] share
                const __bf16* g = kgbase + (size_t)(ch + 1) * 16384;
                __bf16* l = (__bf16*)k_lds[(ch + 1) & 1] + wid * 2048;
                #pragma unroll
                for (int i = 0; i < 4; i++)
                    stage16(g + i * 512, l + i * 512);
            }
            if (ch > 0) {
                int cc = ch - 1;
                // V loads issued at phase start; covered by pf reads + MFMAs.
                bf16x8 vf[2][4];
                #pragma unroll
                for (int ct = 0; ct < 2; ct++)
                    #pragma unroll
                    for (int ks4 = 0; ks4 < 4; ks4++) {
                        size_t off = (size_t)(cc * 2 + (ks4 >> 1)) * 8192
                                   + (size_t)(ks4 & 1) * 4096 + (cw * 2 + ct) * 256;
                        vf[ct][ks4] = *(const bf16x8*)(vbase + off);
                    }
                const char* pbuf = (const char*)p_lds[cc & 1];
                __builtin_amdgcn_s_setprio(1);
                #pragma unroll
                for (int rt = 0; rt < 2; rt++) {
                    int prow = rt * 32 + n31;
                    int swz  = (prow & 7) << 4;
                    int pbs  = prow * 128 + q2 * 16;
                    #pragma unroll
                    for (int ks4 = 0; ks4 < 4; ks4++) {
                        bf16x8 pf = *(const bf16x8*)(pbuf + ((pbs + ks4 * 32) ^ swz));
                        o_acc[0][rt] = __builtin_amdgcn_mfma_f32_32x32x16_bf16(
                            vf[0][ks4], pf, o_acc[0][rt], 0, 0, 0);
                        o_acc[1][rt] = __builtin_amdgcn_mfma_f32_32x32x16_bf16(
                            vf[1][ks4], pf, o_acc[1][rt], 0, 0, 0);
                    }
                }
                __builtin_amdgcn_s_setprio(0);
            }
        }
        __syncthreads();                     // pairs with producer tail barrier
        // l for rows n31 and 32+n31 (kt slots summed); L2-hit, hidden by tail.
        float lA = lt[n31] + lt[64 + n31];
        float lB = lt[32 + n31] + lt[64 + 32 + n31];
        {   // tail: consume chunk 31 from p_lds[1]
            int cc = NCH - 1;
            bf16x8 vf[2][4];
            #pragma unroll
            for (int ct = 0; ct < 2; ct++)
                #pragma unroll
                for (int ks4 = 0; ks4 < 4; ks4++) {
                    size_t off = (size_t)(cc * 2 + (ks4 >> 1)) * 8192
                               + (size_t)(ks4 & 1) * 4096 + (cw * 2 + ct) * 256;
                    vf[ct][ks4] = *(const bf16x8*)(vbase + off);
                }
            const char* pbuf = (const char*)p_lds[1];
            __builtin_amdgcn_s_setprio(1);
            #pragma unroll
            for (int rt = 0; rt < 2; rt++) {
                int prow = rt * 32 + n31;
                int swz  = (prow & 7) << 4;
                int pbs  = prow * 128 + q2 * 16;
                #pragma unroll
                for (int ks4 = 0; ks4 < 4; ks4++) {
                    bf16x8 pf = *(const bf16x8*)(pbuf + ((pbs + ks4 * 32) ^ swz));
                    o_acc[0][rt] = __builtin_amdgcn_mfma_f32_32x32x16_bf16(
                        vf[0][ks4], pf, o_acc[0][rt], 0, 0, 0);
                    o_acc[1][rt] = __builtin_amdgcn_mfma_f32_32x32x16_bf16(
                        vf[1][ks4], pf, o_acc[1][rt], 0, 0, 0);
                }
            }
            __builtin_amdgcn_s_setprio(0);
        }
        // lpart plane for proj (one consumer wave).
        if (wid == 4 && lane < 32) {
            float* lp = lpart + ((size_t)split * B_ + b) * N_ + n0;
            lp[n31]      = lA;
            lp[32 + n31] = lB;
        }
        // Normalize by split-local l, store bf16 partials (plane per split).
        float inv0 = 1.0f / lA;
        float inv1 = 1.0f / lB;
        __bf16* aop = aob + (size_t)split * PLANE;
        #pragma unroll
        for (int ct = 0; ct < 2; ct++)
            #pragma unroll
            for (int rt = 0; rt < 2; rt++) {
                float inv = rt ? inv1 : inv0;
                #pragma unroll
                for (int g = 0; g < 4; g++) {
                    bf16x4 st;
                    #pragma unroll
                    for (int j = 0; j < 4; j++)
                        st[j] = (__bf16)(o_acc[ct][rt][g * 4 + j] * inv);
                    size_t idx = ((((((size_t)(b * 64 + qt) * 4 + cw) * 2 + ct) * 2 + rt)
                                   * 4 + g) * 2 + q2) * 128 + n31 * 4;
                    *(bf16x4*)(aop + idx) = st;
                }
            }
    }
}

// ---------------------------------------------------------------------------
// Kernel 4 (R9): out projection, 2 tiles/block, grid 512 -> 2 blocks/CU
// (was 1 block/CU = 1 wave/SIMD, no latency hiding). Body unchanged.
// ---------------------------------------------------------------------------
__global__ __launch_bounds__(256) void proj_kernel(const __bf16* __restrict__ aob,
                                                   const float* __restrict__ lpart,
                                                   const float* __restrict__ W2,
                                                   const float* __restrict__ bias,
                                                   const float* __restrict__ x,
                                                   float* __restrict__ out) {
    int bid = blockIdx.x;                      // 0..511
    int b   = (bid & 7) >> 1;
    int u   = ((bid >> 3) << 1) | (bid & 1);   // 0..127
    int ot  = u >> 6;                          // 0..1
    int tp  = u & 63;                          // 0..63 (tile pair)
    int tid = threadIdx.x, wv = tid >> 6, lane = tid & 63;
    int n31 = lane & 31, q2 = lane >> 5;
    int B0 = ot * 128 + wv * 32;
    const size_t BN = (size_t)B_ * N_;
    const size_t PLANE = (size_t)B_ * C_ * N_;

    bf16x8 wf[16];
    const float* wp = W2 + (size_t)(B0 + n31) * C_;
    #pragma unroll
    for (int ks = 0; ks < 16; ks++) {
        float4 t0 = *(const float4*)(wp + ks * 16 + q2 * 8);
        float4 t1 = *(const float4*)(wp + ks * 16 + q2 * 8 + 4);
        bf16x8 f;
        f[0] = (__bf16)t0.x; f[1] = (__bf16)t0.y; f[2] = (__bf16)t0.z; f[3] = (__bf16)t0.w;
        f[4] = (__bf16)t1.x; f[5] = (__bf16)t1.y; f[6] = (__bf16)t1.z; f[7] = (__bf16)t1.w;
        wf[ks] = f;
    }
    float bv[16];
    #pragma unroll
    for (int r = 0; r < 16; r++) bv[r] = bias[B0 + (r & 3) + 8 * (r >> 2) + 4 * q2];

    for (int t = 0; t < 2; t++) {
        int nt = tp * 2 + t;                  // 32-row tile, 0..127
        int qt = nt >> 1, rtile = nt & 1;
        int n = nt * 32 + n31;
        size_t ln = (size_t)b * N_ + n;
        float l0v = lpart[ln];
        float l1v = lpart[BN + ln];
        float invt = 1.0f / (l0v + l1v);
        float w0 = l0v * invt, w1 = l1v * invt;

        bf16x8 xf[16];
        #pragma unroll
        for (int ks = 0; ks < 16; ks++) {
            int oct = ks * 2 + q2;            // chan octet 0..31
            int cw = oct >> 3, ct = (oct >> 2) & 1, ga = oct & 3;
            size_t base = ((((((size_t)(b * 64 + qt) * 4 + cw) * 2 + ct) * 2 + rtile)
                            * 4 + ga) * 2) * 128 + n31 * 4;
            bf16x4 a0 = *(const bf16x4*)(aob + base);
            bf16x4 b0 = *(const bf16x4*)(aob + base + 128);
            bf16x4 a1 = *(const bf16x4*)(aob + PLANE + base);
            bf16x4 b1 = *(const bf16x4*)(aob + PLANE + base + 128);
            bf16x8 f;
            #pragma unroll
            for (int j = 0; j < 4; j++) {
                f[j]     = (__bf16)(w0 * (float)a0[j] + w1 * (float)a1[j]);
                f[4 + j] = (__bf16)(w0 * (float)b0[j] + w1 * (float)b1[j]);
            }
            xf[ks] = f;
        }

        f32x16 acc;
        #pragma unroll
        for (int i = 0; i < 16; i++) acc[i] = 0.f;
        #pragma unroll
        for (int ks = 0; ks < 16; ks++)
            acc = __builtin_amdgcn_mfma_f32_32x32x16_bf16(wf[ks], xf[ks], acc, 0, 0, 0);

        #pragma unroll
        for (int r = 0; r < 16; r++) {
            int o = B0 + (r & 3) + 8 * (r >> 2) + 4 * q2;
            size_t idx = ((size_t)(b * C_ + o)) * N_ + nt * 32 + n31;
            out[idx] = acc[r] + bv[r] + x[idx];
        }
    }
}

// ---------------------------------------------------------------------------
extern "C" void kernel_launch(void* const* d_in, const int* in_sizes, int n_in,
                              void* d_out, int out_size, void* d_ws, size_t ws_size,
                              hipStream_t stream) {
    const float* x     = (const float*)d_in[0];
    const float* gn_w  = (const float*)d_in[1];
    const float* gn_b  = (const float*)d_in[2];
    const float* qkv_w = (const float*)d_in[3];
    const float* qkv_b = (const float*)d_in[4];
    const float* out_w = (const float*)d_in[5];
    const float* out_b = (const float*)d_in[6];
    float* out = (float*)d_out;

    const size_t SZ = (size_t)B_ * C_ * N_;       // 4,194,304 elements
    char* base = (char*)d_ws;
    __bf16* aob = (__bf16*)base;                  // 2 bf16 planes = 16.8 MB
    __bf16* xnb = (__bf16*)base;                  // aliases aob (dead by attn)
    __bf16* qb  = (__bf16*)(base + 2 * SZ * 4);   // 8.39 MB each
    __bf16* kb  = qb + SZ;
    __bf16* vb  = kb + SZ;
    float*  lpart = (float*)(base + 2 * SZ * 4 + 3 * SZ * 2);  // [2][B][N] fp32
    float*  part  = lpart + 2 * (size_t)B_ * N_;  // [512][2] GN partials
    float*  ltmp  = part + 1024;                  // [512][128] l scratch, 256 KB

    gn_stats_kernel<<<dim3(512), 256, 0, stream>>>(x, part);
    gn_apply_kernel<<<dim3(512), 256, 0, stream>>>(x, gn_w, gn_b, part, xnb);
    qkv_kernel<<<dim3(768), 256, 0, stream>>>(xnb, qkv_w, qkv_b, qb, kb, vb);
    attn_kernel<<<dim3(512), 512, 0, stream>>>(qb, kb, vb, aob, lpart, ltmp);
    proj_kernel<<<dim3(512), 256, 0, stream>>>(aob, lpart, out_w, out_b, x, out);
}